// Round 4
// baseline (2245.826 us; speedup 1.0000x reference)
//
#include <hip/hip_runtime.h>
#include <math.h>

#define NP   10
#define C_   64
#define H_   128
#define W_   128
#define HW   (H_*W_)
#define DG_  16
#define CG_  4
#define K_   9
#define MRM_ 10.0f

#define S1 (130*9*64)
#define S2 (64*9*64)

// dynamic-LDS layout for k_dcn4
#define AHI_OFF 0u
#define ALO_OFF 41472u
#define SV_OFF  82944u
#define OMB_OFF 107520u
#define FLT_OFF 135168u
#define LDS_TOT 137216

typedef __bf16 bf16x8 __attribute__((ext_vector_type(8)));
typedef float  f32x16 __attribute__((ext_vector_type(16)));

__device__ __forceinline__ f32x16 mfma32(bf16x8 a, bf16x8 b, f32x16 c) {
    return __builtin_amdgcn_mfma_f32_32x32x16_bf16(a, b, c, 0, 0, 0);
}

__device__ __forceinline__ ushort bfrn(float f) {
    uint u = __builtin_bit_cast(uint, f);
    u += 0x7FFFu + ((u >> 16) & 1u);
    return (ushort)(u >> 16);
}
__device__ __forceinline__ float bf2f(ushort h) {
    uint u = (uint)h << 16; return __builtin_bit_cast(float, u);
}
__device__ __forceinline__ float fast_tanh(float x) {
    float e = __expf(2.f * x);
    return 1.f - 2.f / (e + 1.f);
}

// ---------- frame-mapping helpers ----------
__device__ __forceinline__ const float* xi_base(const float* x, int n) {
    int f = (n < 5) ? (n + 1) : (n - 5);
    return x + (size_t)f * C_ * HW;
}
__device__ __forceinline__ const float* cur_base(const float* x, int n) {
    int f = (n < 5) ? n : (n - 4);
    return x + (size_t)f * C_ * HW;
}
__device__ __forceinline__ const float* fl_base(const float* fb, const float* ff, int n) {
    return (n < 5) ? (fb + (size_t)n * 2 * HW) : (ff + (size_t)(n - 5) * 2 * HW);
}

// ---------- bilinear corner helper (zero padding outside) ----------
struct Bil { int i00, i01, i10, i11; float m00, m01, m10, m11; };
__device__ __forceinline__ Bil bil(float py, float px) {
    float y0f = floorf(py), x0f = floorf(px);
    int iy0 = (int)y0f, ix0 = (int)x0f;
    float ay = py - y0f, ax = px - x0f;
    bool v0y = (unsigned)iy0 < (unsigned)H_;
    bool v1y = (unsigned)(iy0 + 1) < (unsigned)H_;
    bool v0x = (unsigned)ix0 < (unsigned)W_;
    bool v1x = (unsigned)(ix0 + 1) < (unsigned)W_;
    int cy0 = min(max(iy0, 0), H_ - 1), cy1 = min(max(iy0 + 1, 0), H_ - 1);
    int cx0 = min(max(ix0, 0), W_ - 1), cx1 = min(max(ix0 + 1, 0), W_ - 1);
    Bil r;
    r.m00 = (1.f - ay) * (1.f - ax) * (float)(v0y && v0x);
    r.m01 = (1.f - ay) * ax         * (float)(v0y && v1x);
    r.m10 = ay * (1.f - ax)         * (float)(v1y && v0x);
    r.m11 = ay * ax                 * (float)(v1y && v1x);
    r.i00 = cy0 * W_ + cx0; r.i01 = cy0 * W_ + cx1;
    r.i10 = cy1 * W_ + cx0; r.i11 = cy1 * W_ + cx1;
    return r;
}

// ---------- weight transpose prep (f32, conv1-3) ----------
__global__ __launch_bounds__(256) void k_prep1(
        const float* __restrict__ cw1, const float* __restrict__ cw2,
        const float* __restrict__ cw3,
        float* __restrict__ cw1t, float* __restrict__ cw2t,
        float* __restrict__ cw3t) {
    int id = blockIdx.x * 256 + threadIdx.x;
    if (id < S1) {
        int co = id & 63, r = id >> 6; int k = r % 9, ci = r / 9;
        cw1t[id] = cw1[(co * 130 + ci) * 9 + k]; return;
    }
    id -= S1;
    if (id < S2) {
        int co = id & 63, r = id >> 6; int k = r % 9, ci = r / 9;
        cw2t[id] = cw2[(co * 64 + ci) * 9 + k]; return;
    }
    id -= S2;
    if (id < S2) {
        int co = id & 63, r = id >> 6; int k = r % 9, ci = r / 9;
        cw3t[id] = cw3[(co * 64 + ci) * 9 + k]; return;
    }
}

// ---------- MFMA fragment-order weight prep (conv4 hi/lo + dcn + bias) ----------
__global__ __launch_bounds__(256) void k_prep4(
        const float* __restrict__ cw4, const float* __restrict__ cb4,
        const float* __restrict__ dw,
        ushort* __restrict__ w4hi, ushort* __restrict__ w4lo,
        ushort* __restrict__ dwtb, float* __restrict__ pb4) {
    int id = blockIdx.x * 256 + threadIdx.x;
    if (id < 294912) {
        int blk = id >> 9, e = id & 511;
        int c = blk / 144, r = blk - c * 144;
        int t = r >> 4, g = r & 15;
        int l = e >> 3, j = e & 7;
        int n = l & 31, kh = l >> 5;
        int ci = c * 16 + kh * 8 + j;
        int ch = (n < 18) ? g * 18 + n : (n < 27 ? 288 + g * 9 + (n - 18) : -1);
        float v = (ch >= 0) ? cw4[((size_t)ch * 64 + ci) * 9 + t] : 0.f;
        ushort h = bfrn(v);
        w4hi[id] = h;
        w4lo[id] = bfrn(v - bf2f(h));
        return;
    }
    id -= 294912;
    if (id < 49152) {
        int blk = id >> 9, e = id & 511;
        int g = blk / 6, r = blk - g * 6;
        int kst = r >> 1, nf = r & 1;
        int l = e >> 3, j = e & 7;
        int kk = kst * 16 + (l >> 5) * 8 + j;
        int oc = nf * 32 + (l & 31);
        float v = (kk < 36) ? dw[((size_t)oc * 64 + g * 4 + (kk & 3)) * 9 + (kk >> 2)] : 0.f;
        dwtb[id] = bfrn(v);
        return;
    }
    id -= 49152;
    if (id < 512) {
        int g = id >> 5, n = id & 31;
        int ch = (n < 18) ? g * 18 + n : (n < 27 ? 288 + g * 9 + (n - 18) : -1);
        pb4[id] = (ch >= 0) ? cb4[ch] : 0.f;
    }
}

// ---------- flow warp ----------
__global__ __launch_bounds__(256) void k_warp(
        const float* __restrict__ x, const float* __restrict__ fb,
        const float* __restrict__ ff, float* __restrict__ warped) {
    int gid = blockIdx.x * 256 + threadIdx.x;
    int n = gid / HW, pos = gid % HW;
    int y = pos / W_, xx = pos % W_;
    const float* fl = fl_base(fb, ff, n);
    float fx = fl[pos], fy = fl[HW + pos];
    Bil b = bil((float)y + fy, (float)xx + fx);
    const float* xb = xi_base(x, n);
    float* wout = warped + (size_t)n * C_ * HW + pos;
    for (int c = 0; c < C_; ++c) {
        const float* p = xb + c * HW;
        wout[c * HW] = b.m00 * p[b.i00] + b.m01 * p[b.i01]
                     + b.m10 * p[b.i10] + b.m11 * p[b.i11];
    }
}

// ---------- generic 3x3 conv (f32 VALU), 64 out channels, LeakyReLU(0.1) ----------
template<int CIN, int SRC>
__global__ __launch_bounds__(256) void k_conv(
        const float* __restrict__ in, const float* __restrict__ x,
        const float* __restrict__ fb, const float* __restrict__ ff,
        const float* __restrict__ wt, const float* __restrict__ bias,
        float* __restrict__ outp) {
    __shared__ __align__(16) float tile[18 * 18];
    __shared__ __align__(16) float wl[9 * 64];
    int tid = threadIdx.x;
    int bx = blockIdx.x & 7, by = (blockIdx.x >> 3) & 7, n = blockIdx.x >> 6;
    int tx = tid & 15, ty = tid >> 4;
    int X = bx * 16 + tx, Y = by * 16 + ty;
    float acc[64];
    #pragma unroll
    for (int i = 0; i < 64; ++i) acc[i] = 0.f;

    for (int ci = 0; ci < CIN; ++ci) {
        const float* src;
        if (SRC == 0) {
            if (ci < 64)       src = in + ((size_t)n * 64 + ci) * HW;
            else if (ci < 128) src = cur_base(x, n) + (size_t)(ci - 64) * HW;
            else               src = fl_base(fb, ff, n) + (size_t)(ci - 128) * HW;
        } else {
            src = in + ((size_t)n * 64 + ci) * HW;
        }
        for (int i = tid; i < 18 * 18; i += 256) {
            int yy = i / 18, xx = i % 18;
            int gy = by * 16 + yy - 1, gx = bx * 16 + xx - 1;
            tile[i] = (gy >= 0 && gy < H_ && gx >= 0 && gx < W_) ? src[gy * W_ + gx] : 0.f;
        }
        for (int i = tid; i < 576; i += 256) wl[i] = wt[(size_t)ci * 576 + i];
        __syncthreads();

        float win[9];
        #pragma unroll
        for (int ky = 0; ky < 3; ++ky)
            #pragma unroll
            for (int kx = 0; kx < 3; ++kx)
                win[ky * 3 + kx] = tile[(ty + ky) * 18 + tx + kx];

        #pragma unroll
        for (int k = 0; k < 9; ++k) {
            float wv = win[k];
            #pragma unroll
            for (int c4 = 0; c4 < 16; ++c4) {
                float4 wq = *(const float4*)&wl[k * 64 + c4 * 4];
                acc[c4 * 4 + 0] += wq.x * wv;
                acc[c4 * 4 + 1] += wq.y * wv;
                acc[c4 * 4 + 2] += wq.z * wv;
                acc[c4 * 4 + 3] += wq.w * wv;
            }
        }
        __syncthreads();
    }
    float* op = outp + (size_t)n * 64 * HW + Y * W_ + X;
    #pragma unroll
    for (int co = 0; co < 64; ++co) {
        float v = acc[co] + bias[co];
        v = (v >= 0.f) ? v : 0.1f * v;
        op[co * HW] = v;
    }
}

// ================== fused conv4(bf16x2 MFMA) + sampler(f32) + DCN GEMM(bf16 MFMA) ==================
// block = 16x16 px tile, 256 threads = 4 waves; wave w owns px rows 4w..4w+3 (Mfrags 2w,2w+1).
// Full h3 halo tile (64 ci, hi+lo bf16) resident in LDS, staged ONCE.
// NOTE: sv is written via uint2* and read via bf16x8* (TBAA says no-alias!) — the
// __syncthreads() in the group loop are REQUIRED as compiler memory barriers
// (removing them in round 3 let hipcc reorder sv reads vs writes -> 0.52 absmax).
__global__ __launch_bounds__(256, 1) void k_dcn4(
        const float* __restrict__ h3, const float* __restrict__ x,
        const float* __restrict__ fb, const float* __restrict__ ff,
        const ushort* __restrict__ w4hi, const ushort* __restrict__ w4lo,
        const ushort* __restrict__ dwtb, const float* __restrict__ pb4,
        const float* __restrict__ db, float* __restrict__ outb) {
    extern __shared__ __align__(16) char lds[];
    float* OMB = (float*)(lds + OMB_OFF);
    float* FLT = (float*)(lds + FLT_OFF);

    int tid = threadIdx.x;
    int lane = tid & 63, w = tid >> 6;
    // bijective XCD swizzle: 640 blocks, 8 XCDs -> each XCD gets 80 consecutive ids
    int id = (blockIdx.x & 7) * 80 + (blockIdx.x >> 3);
    int bx = id & 7, by = (id >> 3) & 7, n = id >> 6;
    int col = lane & 31, khalf = lane >> 5;

    const float* h3n = h3 + (size_t)n * 64 * HW;
    const float* fl = fl_base(fb, ff, n);
    const float* xg0 = xi_base(x, n);

    // ---- stage flow tile + zero sv K-pad slots (kk 36..47)
    {
        int Y = by * 16 + (tid >> 4), X = bx * 16 + (tid & 15);
        FLT[tid] = fl[Y * W_ + X];
        FLT[256 + tid] = fl[HW + Y * W_ + X];
        uint pb = SV_OFF + (uint)tid * 96 + 72;
        *(unsigned long long*)(lds + pb)      = 0ull;
        *(unsigned long long*)(lds + pb + 8)  = 0ull;
        *(unsigned long long*)(lds + pb + 16) = 0ull;
    }

    // ---- stage full h3 halo tile: [cell 324][ci 64] bf16 hi/lo, XOR-swizzled 16B units
    for (int c = 0; c < 4; ++c) {
        for (int v = 0; v < 6; ++v) {
            int cell = v * 64 + lane;
            if (cell < 324) {
                int cy = cell / 18, cx = cell - cy * 18;
                int gy = by * 16 + cy - 1, gx = bx * 16 + cx - 1;
                bool ok = ((unsigned)gy < 128u) && ((unsigned)gx < 128u);
                const float* srcp = h3n + (size_t)(c * 16 + w * 4) * HW + gy * W_ + gx;
                uint2 hv, lv;
                hv.x = hv.y = lv.x = lv.y = 0;
                #pragma unroll
                for (int q = 0; q < 4; ++q) {
                    float f = ok ? srcp[q * HW] : 0.f;
                    ushort h = bfrn(f);
                    ushort lo = bfrn(f - bf2f(h));
                    if (q == 0) { hv.x |= h; lv.x |= lo; }
                    else if (q == 1) { hv.x |= (uint)h << 16; lv.x |= (uint)lo << 16; }
                    else if (q == 2) { hv.y |= h; lv.y |= lo; }
                    else { hv.y |= (uint)h << 16; lv.y |= (uint)lo << 16; }
                }
                uint byte = (uint)cell * 128 + (uint)c * 32 + (uint)w * 8;
                byte ^= ((uint)(cell & 7)) << 4;
                *(uint2*)(lds + byte) = hv;
                *(uint2*)(lds + ALO_OFF + byte) = lv;
            }
        }
    }
    __syncthreads();   // A tile + FLT + sv-pad visible to all; A is read-only after this

    f32x16 zero16;
    #pragma unroll
    for (int r = 0; r < 16; ++r) zero16[r] = 0.f;

    f32x16 cd[2][2];   // persistent DCN acc [Mf f][Nf]
    #pragma unroll
    for (int a = 0; a < 2; ++a)
        #pragma unroll
        for (int b = 0; b < 2; ++b) cd[a][b] = zero16;

    int xb2 = col & 15;
    int rb0 = 4 * w + ((col >> 4) & 1);   // + 2*f + ky -> cell row

    for (int sp = 0; sp < 8; ++sp) {
        int g0 = sp * 2;
        f32x16 c4[2][2];   // [gg][f]
        #pragma unroll
        for (int a = 0; a < 2; ++a)
            #pragma unroll
            for (int b = 0; b < 2; ++b) c4[a][b] = zero16;

        // ---- conv4 MFMA sweep: A resident in LDS, B frags streamed from global (L2)
        #pragma unroll 1
        for (int c = 0; c < 4; ++c) {
            #pragma unroll
            for (int t = 0; t < 9; ++t) {
                const int ky = t / 3, kx = t % 3;
                size_t bb = (size_t)((c * 9 + t) * 16) * 512 + (size_t)lane * 8;
                bf16x8 bh0 = *(const bf16x8*)(w4hi + bb + (size_t)g0 * 512);
                bf16x8 bl0 = *(const bf16x8*)(w4lo + bb + (size_t)g0 * 512);
                bf16x8 bh1 = *(const bf16x8*)(w4hi + bb + (size_t)(g0 + 1) * 512);
                bf16x8 bl1 = *(const bf16x8*)(w4lo + bb + (size_t)(g0 + 1) * 512);
                #pragma unroll
                for (int f = 0; f < 2; ++f) {
                    int cell = (rb0 + 2 * f + ky) * 18 + xb2 + kx;
                    uint byte = (uint)cell * 128 + (uint)(2 * c + khalf) * 16;
                    byte ^= ((uint)(cell & 7)) << 4;
                    bf16x8 ah = *(const bf16x8*)(lds + byte);
                    bf16x8 al = *(const bf16x8*)(lds + ALO_OFF + byte);
                    c4[0][f] = mfma32(ah, bh0, c4[0][f]);
                    c4[0][f] = mfma32(al, bh0, c4[0][f]);
                    c4[0][f] = mfma32(ah, bl0, c4[0][f]);
                    c4[1][f] = mfma32(ah, bh1, c4[1][f]);
                    c4[1][f] = mfma32(al, bh1, c4[1][f]);
                    c4[1][f] = mfma32(ah, bl1, c4[1][f]);
                }
            }
        }

        // ---- per group: om dump -> sample -> dcn gemm (barriers = compiler fences, see note)
        #pragma unroll
        for (int gg = 0; gg < 2; ++gg) {
            int g = g0 + gg;
            __syncthreads();   // prev gemm sv/omb reads done; fence vs following writes
            if (col < 27) {
                float pb = pb4[g * 32 + col];
                #pragma unroll
                for (int f = 0; f < 2; ++f)
                    #pragma unroll
                    for (int r = 0; r < 16; ++r) {
                        int pxl = 64 * w + 32 * f + (r & 3) + 8 * (r >> 2) + 4 * khalf;
                        float v = c4[gg][f][r] + pb;
                        v = (col < 18) ? MRM_ * fast_tanh(v) : 1.f / (1.f + __expf(-v));
                        OMB[pxl * 27 + col] = v;
                    }
            }
            __syncthreads();   // om visible
            // ---- sampler: 1 px per thread, f32
            {
                int px = tid;
                float fx = FLT[px], fy = FLT[256 + px];
                float Yf = (float)(by * 16 + (px >> 4));
                float Xf = (float)(bx * 16 + (px & 15));
                const float* gb = xg0 + (size_t)(g * 4) * HW;
                #pragma unroll
                for (int k = 0; k < 9; ++k) {
                    float oy = OMB[px * 27 + 2 * k] + fy;
                    float ox = OMB[px * 27 + 2 * k + 1] + fx;
                    float mk = OMB[px * 27 + 18 + k];
                    Bil b = bil(Yf - 1.f + (float)(k / 3) + oy,
                                Xf - 1.f + (float)(k % 3) + ox);
                    uint2 pk; pk.x = 0; pk.y = 0;
                    #pragma unroll
                    for (int cc = 0; cc < 4; ++cc) {
                        const float* p = gb + (size_t)cc * HW;
                        float s = (b.m00 * p[b.i00] + b.m01 * p[b.i01]
                                 + b.m10 * p[b.i10] + b.m11 * p[b.i11]) * mk;
                        ushort hv = bfrn(s);
                        if (cc == 0) pk.x |= hv;
                        else if (cc == 1) pk.x |= (uint)hv << 16;
                        else if (cc == 2) pk.y |= hv;
                        else pk.y |= (uint)hv << 16;
                    }
                    *(uint2*)(lds + (SV_OFF + (uint)px * 96 + (uint)k * 8)) = pk;
                }
            }
            __syncthreads();   // sv visible (and fences uint2 stores vs bf16x8 loads)
            // ---- DCN GEMM: A = sv (bf16), B = dwt frags from global
            #pragma unroll
            for (int kst = 0; kst < 3; ++kst) {
                size_t dbb = (size_t)((g * 3 + kst) * 2) * 512 + (size_t)lane * 8;
                bf16x8 b0 = *(const bf16x8*)(dwtb + dbb);
                bf16x8 b1 = *(const bf16x8*)(dwtb + dbb + 512);
                #pragma unroll
                for (int f = 0; f < 2; ++f) {
                    int pxl = 64 * w + 32 * f + col;
                    uint byte = SV_OFF + (uint)pxl * 96 + (uint)(kst * 2 + khalf) * 16;
                    bf16x8 a = *(const bf16x8*)(lds + byte);
                    cd[f][0] = mfma32(a, b0, cd[f][0]);
                    cd[f][1] = mfma32(a, b1, cd[f][1]);
                }
            }
        }
    }

    // ---- epilogue: bias + store to output frame slot
    float* base = (n < 5) ? outb + (size_t)n * 64 * HW
                          : outb + (size_t)(n + 2) * 64 * HW;
    #pragma unroll
    for (int f = 0; f < 2; ++f)
        #pragma unroll
        for (int nf = 0; nf < 2; ++nf) {
            int oc = nf * 32 + col;
            float bias = db[oc];
            #pragma unroll
            for (int r = 0; r < 16; ++r) {
                int pxl = 64 * w + 32 * f + (r & 3) + 8 * (r >> 2) + 4 * khalf;
                int y = by * 16 + (pxl >> 4), xx = bx * 16 + (pxl & 15);
                base[(size_t)oc * HW + y * W_ + xx] = cd[f][nf][r] + bias;
            }
        }
}

extern "C" void kernel_launch(void* const* d_in, const int* in_sizes, int n_in,
                              void* d_out, int out_size, void* d_ws, size_t ws_size,
                              hipStream_t stream) {
    (void)in_sizes; (void)n_in; (void)out_size; (void)ws_size;
    const float* x   = (const float*)d_in[0];
    const float* fb  = (const float*)d_in[1];
    const float* ff  = (const float*)d_in[2];
    const float* cw1 = (const float*)d_in[3];
    const float* cb1 = (const float*)d_in[4];
    const float* cw2 = (const float*)d_in[5];
    const float* cb2 = (const float*)d_in[6];
    const float* cw3 = (const float*)d_in[7];
    const float* cb3 = (const float*)d_in[8];
    const float* cw4 = (const float*)d_in[9];
    const float* cb4 = (const float*)d_in[10];
    const float* dw  = (const float*)d_in[11];
    const float* db  = (const float*)d_in[12];
    float* out = (float*)d_out;
    float* ws  = (float*)d_ws;

    // ws layout: bufB (10485760 f32) | cw1t | cw2t | cw3t | w4hi | w4lo | dwtb | pb4
    float* bufA = out;
    float* bufB = ws;
    float* cw1t = ws + 10485760;
    float* cw2t = cw1t + S1;
    float* cw3t = cw2t + S2;
    ushort* w4hi = (ushort*)(cw3t + S2);       // 294912 ushorts
    ushort* w4lo = w4hi + 294912;
    ushort* dwtb = w4lo + 294912;              // 49152 ushorts
    float*  pb4  = (float*)(dwtb + 49152);     // 512 f32

    // allow >64KB dynamic LDS (host-side attribute set; not a stream op -> capture-safe;
    // called unconditionally each launch, deterministic)
    (void)hipFuncSetAttribute((const void*)k_dcn4,
                              hipFuncAttributeMaxDynamicSharedMemorySize, LDS_TOT);

    k_prep1<<<(S1 + 2 * S2 + 255) / 256, 256, 0, stream>>>(cw1, cw2, cw3, cw1t, cw2t, cw3t);
    k_prep4<<<1346, 256, 0, stream>>>(cw4, cb4, dw, w4hi, w4lo, dwtb, pb4);
    k_warp<<<(NP * HW) / 256, 256, 0, stream>>>(x, fb, ff, bufA);
    k_conv<130, 0><<<640, 256, 0, stream>>>(bufA, x, fb, ff, cw1t, cb1, bufB);
    k_conv<64, 1><<<640, 256, 0, stream>>>(bufB, x, fb, ff, cw2t, cb2, bufA);
    k_conv<64, 1><<<640, 256, 0, stream>>>(bufA, x, fb, ff, cw3t, cb3, bufB);

    // zero output frame slots 5 (backward last) and 6 (forward first)
    hipMemsetAsync((char*)d_out + (size_t)5 * C_ * HW * sizeof(float), 0, (size_t)C_ * HW * sizeof(float), stream);
    hipMemsetAsync((char*)d_out + (size_t)6 * C_ * HW * sizeof(float), 0, (size_t)C_ * HW * sizeof(float), stream);

    k_dcn4<<<640, 256, LDS_TOT, stream>>>(bufB, x, fb, ff, w4hi, w4lo, dwtb, pb4, db, out);
}

// Round 5
// 1714.767 us; speedup vs baseline: 1.3097x; 1.3097x over previous
//
#include <hip/hip_runtime.h>
#include <math.h>

#define NP   10
#define C_   64
#define H_   128
#define W_   128
#define HW   (H_*W_)
#define DG_  16
#define CG_  4
#define K_   9
#define MRM_ 10.0f

#define S1 (130*9*64)
#define S2 (64*9*64)

// dynamic-LDS layout for k_dcn5 (81408 B -> 2 blocks/CU on 160KB LDS)
#define A_OFF   0u
#define SV_OFF  41472u
#define OMB_OFF 66048u
#define LDS_TOT 81408

typedef __bf16 bf16x8 __attribute__((ext_vector_type(8)));
typedef float  f32x16 __attribute__((ext_vector_type(16)));

__device__ __forceinline__ f32x16 mfma32(bf16x8 a, bf16x8 b, f32x16 c) {
    return __builtin_amdgcn_mfma_f32_32x32x16_bf16(a, b, c, 0, 0, 0);
}

__device__ __forceinline__ ushort bfrn(float f) {
    uint u = __builtin_bit_cast(uint, f);
    u += 0x7FFFu + ((u >> 16) & 1u);
    return (ushort)(u >> 16);
}
__device__ __forceinline__ float bf2f(ushort h) {
    uint u = (uint)h << 16; return __builtin_bit_cast(float, u);
}
__device__ __forceinline__ float fast_tanh(float x) {
    float e = __expf(2.f * x);
    return 1.f - 2.f / (e + 1.f);
}

// ---------- frame-mapping helpers ----------
__device__ __forceinline__ const float* xi_base(const float* x, int n) {
    int f = (n < 5) ? (n + 1) : (n - 5);
    return x + (size_t)f * C_ * HW;
}
__device__ __forceinline__ const float* cur_base(const float* x, int n) {
    int f = (n < 5) ? n : (n - 4);
    return x + (size_t)f * C_ * HW;
}
__device__ __forceinline__ const float* fl_base(const float* fb, const float* ff, int n) {
    return (n < 5) ? (fb + (size_t)n * 2 * HW) : (ff + (size_t)(n - 5) * 2 * HW);
}

// ---------- bilinear corner helper (zero padding outside) ----------
struct Bil { int i00, i01, i10, i11; float m00, m01, m10, m11; };
__device__ __forceinline__ Bil bil(float py, float px) {
    float y0f = floorf(py), x0f = floorf(px);
    int iy0 = (int)y0f, ix0 = (int)x0f;
    float ay = py - y0f, ax = px - x0f;
    bool v0y = (unsigned)iy0 < (unsigned)H_;
    bool v1y = (unsigned)(iy0 + 1) < (unsigned)H_;
    bool v0x = (unsigned)ix0 < (unsigned)W_;
    bool v1x = (unsigned)(ix0 + 1) < (unsigned)W_;
    int cy0 = min(max(iy0, 0), H_ - 1), cy1 = min(max(iy0 + 1, 0), H_ - 1);
    int cx0 = min(max(ix0, 0), W_ - 1), cx1 = min(max(ix0 + 1, 0), W_ - 1);
    Bil r;
    r.m00 = (1.f - ay) * (1.f - ax) * (float)(v0y && v0x);
    r.m01 = (1.f - ay) * ax         * (float)(v0y && v1x);
    r.m10 = ay * (1.f - ax)         * (float)(v1y && v0x);
    r.m11 = ay * ax                 * (float)(v1y && v1x);
    r.i00 = cy0 * W_ + cx0; r.i01 = cy0 * W_ + cx1;
    r.i10 = cy1 * W_ + cx0; r.i11 = cy1 * W_ + cx1;
    return r;
}

// ---------- weight transpose prep (f32, conv1-3) ----------
__global__ __launch_bounds__(256) void k_prep1(
        const float* __restrict__ cw1, const float* __restrict__ cw2,
        const float* __restrict__ cw3,
        float* __restrict__ cw1t, float* __restrict__ cw2t,
        float* __restrict__ cw3t) {
    int id = blockIdx.x * 256 + threadIdx.x;
    if (id < S1) {
        int co = id & 63, r = id >> 6; int k = r % 9, ci = r / 9;
        cw1t[id] = cw1[(co * 130 + ci) * 9 + k]; return;
    }
    id -= S1;
    if (id < S2) {
        int co = id & 63, r = id >> 6; int k = r % 9, ci = r / 9;
        cw2t[id] = cw2[(co * 64 + ci) * 9 + k]; return;
    }
    id -= S2;
    if (id < S2) {
        int co = id & 63, r = id >> 6; int k = r % 9, ci = r / 9;
        cw3t[id] = cw3[(co * 64 + ci) * 9 + k]; return;
    }
}

// ---------- MFMA fragment-order weight prep (conv4 + dcn + bias) ----------
__global__ __launch_bounds__(256) void k_prep4(
        const float* __restrict__ cw4, const float* __restrict__ cb4,
        const float* __restrict__ dw,
        ushort* __restrict__ w4hi,
        ushort* __restrict__ dwtb, float* __restrict__ pb4) {
    int id = blockIdx.x * 256 + threadIdx.x;
    if (id < 294912) {
        int blk = id >> 9, e = id & 511;
        int c = blk / 144, r = blk - c * 144;
        int t = r >> 4, g = r & 15;
        int l = e >> 3, j = e & 7;
        int n = l & 31, kh = l >> 5;
        int ci = c * 16 + kh * 8 + j;
        int ch = (n < 18) ? g * 18 + n : (n < 27 ? 288 + g * 9 + (n - 18) : -1);
        float v = (ch >= 0) ? cw4[((size_t)ch * 64 + ci) * 9 + t] : 0.f;
        w4hi[id] = bfrn(v);
        return;
    }
    id -= 294912;
    if (id < 49152) {
        int blk = id >> 9, e = id & 511;
        int g = blk / 6, r = blk - g * 6;
        int kst = r >> 1, nf = r & 1;
        int l = e >> 3, j = e & 7;
        int kk = kst * 16 + (l >> 5) * 8 + j;
        int oc = nf * 32 + (l & 31);
        float v = (kk < 36) ? dw[((size_t)oc * 64 + g * 4 + (kk & 3)) * 9 + (kk >> 2)] : 0.f;
        dwtb[id] = bfrn(v);
        return;
    }
    id -= 49152;
    if (id < 512) {
        int g = id >> 5, n = id & 31;
        int ch = (n < 18) ? g * 18 + n : (n < 27 ? 288 + g * 9 + (n - 18) : -1);
        pb4[id] = (ch >= 0) ? cb4[ch] : 0.f;
    }
}

// ---------- flow warp ----------
__global__ __launch_bounds__(256) void k_warp(
        const float* __restrict__ x, const float* __restrict__ fb,
        const float* __restrict__ ff, float* __restrict__ warped) {
    int gid = blockIdx.x * 256 + threadIdx.x;
    int n = gid / HW, pos = gid % HW;
    int y = pos / W_, xx = pos % W_;
    const float* fl = fl_base(fb, ff, n);
    float fx = fl[pos], fy = fl[HW + pos];
    Bil b = bil((float)y + fy, (float)xx + fx);
    const float* xb = xi_base(x, n);
    float* wout = warped + (size_t)n * C_ * HW + pos;
    for (int c = 0; c < C_; ++c) {
        const float* p = xb + c * HW;
        wout[c * HW] = b.m00 * p[b.i00] + b.m01 * p[b.i01]
                     + b.m10 * p[b.i10] + b.m11 * p[b.i11];
    }
}

// ---------- generic 3x3 conv (f32 VALU), 64 out channels, LeakyReLU(0.1) ----------
template<int CIN, int SRC>
__global__ __launch_bounds__(256) void k_conv(
        const float* __restrict__ in, const float* __restrict__ x,
        const float* __restrict__ fb, const float* __restrict__ ff,
        const float* __restrict__ wt, const float* __restrict__ bias,
        float* __restrict__ outp) {
    __shared__ __align__(16) float tile[18 * 18];
    __shared__ __align__(16) float wl[9 * 64];
    int tid = threadIdx.x;
    int bx = blockIdx.x & 7, by = (blockIdx.x >> 3) & 7, n = blockIdx.x >> 6;
    int tx = tid & 15, ty = tid >> 4;
    int X = bx * 16 + tx, Y = by * 16 + ty;
    float acc[64];
    #pragma unroll
    for (int i = 0; i < 64; ++i) acc[i] = 0.f;

    for (int ci = 0; ci < CIN; ++ci) {
        const float* src;
        if (SRC == 0) {
            if (ci < 64)       src = in + ((size_t)n * 64 + ci) * HW;
            else if (ci < 128) src = cur_base(x, n) + (size_t)(ci - 64) * HW;
            else               src = fl_base(fb, ff, n) + (size_t)(ci - 128) * HW;
        } else {
            src = in + ((size_t)n * 64 + ci) * HW;
        }
        for (int i = tid; i < 18 * 18; i += 256) {
            int yy = i / 18, xx = i % 18;
            int gy = by * 16 + yy - 1, gx = bx * 16 + xx - 1;
            tile[i] = (gy >= 0 && gy < H_ && gx >= 0 && gx < W_) ? src[gy * W_ + gx] : 0.f;
        }
        for (int i = tid; i < 576; i += 256) wl[i] = wt[(size_t)ci * 576 + i];
        __syncthreads();

        float win[9];
        #pragma unroll
        for (int ky = 0; ky < 3; ++ky)
            #pragma unroll
            for (int kx = 0; kx < 3; ++kx)
                win[ky * 3 + kx] = tile[(ty + ky) * 18 + tx + kx];

        #pragma unroll
        for (int k = 0; k < 9; ++k) {
            float wv = win[k];
            #pragma unroll
            for (int c4 = 0; c4 < 16; ++c4) {
                float4 wq = *(const float4*)&wl[k * 64 + c4 * 4];
                acc[c4 * 4 + 0] += wq.x * wv;
                acc[c4 * 4 + 1] += wq.y * wv;
                acc[c4 * 4 + 2] += wq.z * wv;
                acc[c4 * 4 + 3] += wq.w * wv;
            }
        }
        __syncthreads();
    }
    float* op = outp + (size_t)n * 64 * HW + Y * W_ + X;
    #pragma unroll
    for (int co = 0; co < 64; ++co) {
        float v = acc[co] + bias[co];
        v = (v >= 0.f) ? v : 0.1f * v;
        op[co * HW] = v;
    }
}

// ================== fused conv4(bf16 MFMA) + sampler(f32) + DCN GEMM(bf16 MFMA) ==================
// block = 16x16 px tile, 256 threads = 4 waves; wave w owns px rows 4w..4w+3 (Mfrags 2w,2w+1).
// Full h3 halo tile (64 ci, single bf16) resident in LDS (41.5KB); total LDS 79.5KB -> 2 blocks/CU.
// NOTE: sv is written via uint2* and read via bf16x8* (TBAA says no-alias!) — the
// __syncthreads() in the group loop are REQUIRED as compiler memory barriers
// (removing them in round 3 let hipcc reorder sv reads vs writes -> 0.52 absmax).
__global__ __launch_bounds__(256, 2) void k_dcn5(
        const float* __restrict__ h3, const float* __restrict__ x,
        const float* __restrict__ fb, const float* __restrict__ ff,
        const ushort* __restrict__ w4hi,
        const ushort* __restrict__ dwtb, const float* __restrict__ pb4,
        const float* __restrict__ db, float* __restrict__ outb) {
    extern __shared__ __align__(16) char lds[];
    _Float16* OMBH = (_Float16*)(lds + OMB_OFF);   // [px 256][30] f16 (stride 30 -> conflict-free)

    int tid = threadIdx.x;
    int lane = tid & 63, w = tid >> 6;
    // bijective XCD swizzle: 640 blocks, 8 XCDs -> each XCD gets 80 consecutive ids
    int id = (blockIdx.x & 7) * 80 + (blockIdx.x >> 3);
    int bx = id & 7, by = (id >> 3) & 7, n = id >> 6;
    int col = lane & 31, khalf = lane >> 5;

    const float* h3n = h3 + (size_t)n * 64 * HW;
    const float* fl = fl_base(fb, ff, n);
    const float* xg0 = xi_base(x, n);

    // ---- per-thread flow (registers; each thread only ever uses its own px)
    int Yp = by * 16 + (tid >> 4), Xp = bx * 16 + (tid & 15);
    float fxr = fl[Yp * W_ + Xp];
    float fyr = fl[HW + Yp * W_ + Xp];

    // ---- zero sv K-pad slots (kk 36..47 -> bytes 72..96 of each px row)
    {
        uint pb = SV_OFF + (uint)tid * 96 + 72;
        *(unsigned long long*)(lds + pb)      = 0ull;
        *(unsigned long long*)(lds + pb + 8)  = 0ull;
        *(unsigned long long*)(lds + pb + 16) = 0ull;
    }

    // ---- stage full h3 halo tile: [cell 324][ci 64] bf16, XOR-swizzled 16B units
    for (int c = 0; c < 4; ++c) {
        for (int v = 0; v < 6; ++v) {
            int cell = v * 64 + lane;
            if (cell < 324) {
                int cy = cell / 18, cx = cell - cy * 18;
                int gy = by * 16 + cy - 1, gx = bx * 16 + cx - 1;
                bool ok = ((unsigned)gy < 128u) && ((unsigned)gx < 128u);
                const float* srcp = h3n + (size_t)(c * 16 + w * 4) * HW + gy * W_ + gx;
                uint2 hv;
                hv.x = hv.y = 0;
                #pragma unroll
                for (int q = 0; q < 4; ++q) {
                    float f = ok ? srcp[q * HW] : 0.f;
                    ushort h = bfrn(f);
                    if (q == 0) hv.x |= h;
                    else if (q == 1) hv.x |= (uint)h << 16;
                    else if (q == 2) hv.y |= h;
                    else hv.y |= (uint)h << 16;
                }
                uint byte = (uint)cell * 128 + (uint)c * 32 + (uint)w * 8;
                byte ^= ((uint)(cell & 7)) << 4;
                *(uint2*)(lds + byte) = hv;
            }
        }
    }
    __syncthreads();   // A tile + sv-pad visible to all; A is read-only after this

    f32x16 zero16;
    #pragma unroll
    for (int r = 0; r < 16; ++r) zero16[r] = 0.f;

    f32x16 cd[2][2];   // persistent DCN acc [Mf f][Nf]
    #pragma unroll
    for (int a = 0; a < 2; ++a)
        #pragma unroll
        for (int b = 0; b < 2; ++b) cd[a][b] = zero16;

    int xb2 = col & 15;
    int rb0 = 4 * w + ((col >> 4) & 1);   // + 2*f + ky -> cell row

    for (int sp = 0; sp < 8; ++sp) {
        int g0 = sp * 2;
        f32x16 c4[2][2];   // [gg][f]
        #pragma unroll
        for (int a = 0; a < 2; ++a)
            #pragma unroll
            for (int b = 0; b < 2; ++b) c4[a][b] = zero16;

        // ---- conv4 MFMA sweep: A resident in LDS, B frags streamed from global (L2)
        #pragma unroll 1
        for (int c = 0; c < 4; ++c) {
            #pragma unroll
            for (int t = 0; t < 9; ++t) {
                const int ky = t / 3, kx = t % 3;
                size_t bb = (size_t)((c * 9 + t) * 16) * 512 + (size_t)lane * 8;
                bf16x8 bh0 = *(const bf16x8*)(w4hi + bb + (size_t)g0 * 512);
                bf16x8 bh1 = *(const bf16x8*)(w4hi + bb + (size_t)(g0 + 1) * 512);
                #pragma unroll
                for (int f = 0; f < 2; ++f) {
                    int cell = (rb0 + 2 * f + ky) * 18 + xb2 + kx;
                    uint byte = (uint)cell * 128 + (uint)(2 * c + khalf) * 16;
                    byte ^= ((uint)(cell & 7)) << 4;
                    bf16x8 ah = *(const bf16x8*)(lds + byte);
                    c4[0][f] = mfma32(ah, bh0, c4[0][f]);
                    c4[1][f] = mfma32(ah, bh1, c4[1][f]);
                }
            }
        }

        // ---- per group: om dump -> sample -> dcn gemm (barriers = compiler fences, see note)
        #pragma unroll
        for (int gg = 0; gg < 2; ++gg) {
            int g = g0 + gg;
            __syncthreads();   // prev gemm sv/omb reads done; fence vs following writes
            if (col < 27) {
                float pb = pb4[g * 32 + col];
                #pragma unroll
                for (int f = 0; f < 2; ++f)
                    #pragma unroll
                    for (int r = 0; r < 16; ++r) {
                        int pxl = 64 * w + 32 * f + (r & 3) + 8 * (r >> 2) + 4 * khalf;
                        float v = c4[gg][f][r] + pb;
                        v = (col < 18) ? MRM_ * fast_tanh(v) : 1.f / (1.f + __expf(-v));
                        OMBH[pxl * 30 + col] = (_Float16)v;
                    }
            }
            __syncthreads();   // om visible
            // ---- sampler: 1 px per thread, f32
            {
                int px = tid;
                float Yf = (float)Yp, Xf = (float)Xp;
                const float* gb = xg0 + (size_t)(g * 4) * HW;
                #pragma unroll
                for (int k = 0; k < 9; ++k) {
                    float oy = (float)OMBH[px * 30 + 2 * k] + fyr;
                    float ox = (float)OMBH[px * 30 + 2 * k + 1] + fxr;
                    float mk = (float)OMBH[px * 30 + 18 + k];
                    Bil b = bil(Yf - 1.f + (float)(k / 3) + oy,
                                Xf - 1.f + (float)(k % 3) + ox);
                    uint2 pk; pk.x = 0; pk.y = 0;
                    #pragma unroll
                    for (int cc = 0; cc < 4; ++cc) {
                        const float* p = gb + (size_t)cc * HW;
                        float s = (b.m00 * p[b.i00] + b.m01 * p[b.i01]
                                 + b.m10 * p[b.i10] + b.m11 * p[b.i11]) * mk;
                        ushort hv = bfrn(s);
                        if (cc == 0) pk.x |= hv;
                        else if (cc == 1) pk.x |= (uint)hv << 16;
                        else if (cc == 2) pk.y |= hv;
                        else pk.y |= (uint)hv << 16;
                    }
                    *(uint2*)(lds + (SV_OFF + (uint)px * 96 + (uint)k * 8)) = pk;
                }
            }
            __syncthreads();   // sv visible (and fences uint2 stores vs bf16x8 loads)
            // ---- DCN GEMM: A = sv (bf16), B = dwt frags from global
            #pragma unroll
            for (int kst = 0; kst < 3; ++kst) {
                size_t dbb = (size_t)((g * 3 + kst) * 2) * 512 + (size_t)lane * 8;
                bf16x8 b0 = *(const bf16x8*)(dwtb + dbb);
                bf16x8 b1 = *(const bf16x8*)(dwtb + dbb + 512);
                #pragma unroll
                for (int f = 0; f < 2; ++f) {
                    int pxl = 64 * w + 32 * f + col;
                    uint byte = SV_OFF + (uint)pxl * 96 + (uint)(kst * 2 + khalf) * 16;
                    bf16x8 a = *(const bf16x8*)(lds + byte);
                    cd[f][0] = mfma32(a, b0, cd[f][0]);
                    cd[f][1] = mfma32(a, b1, cd[f][1]);
                }
            }
        }
    }

    // ---- epilogue: bias + store to output frame slot
    float* base = (n < 5) ? outb + (size_t)n * 64 * HW
                          : outb + (size_t)(n + 2) * 64 * HW;
    #pragma unroll
    for (int f = 0; f < 2; ++f)
        #pragma unroll
        for (int nf = 0; nf < 2; ++nf) {
            int oc = nf * 32 + col;
            float bias = db[oc];
            #pragma unroll
            for (int r = 0; r < 16; ++r) {
                int pxl = 64 * w + 32 * f + (r & 3) + 8 * (r >> 2) + 4 * khalf;
                int y = by * 16 + (pxl >> 4), xx = bx * 16 + (pxl & 15);
                base[(size_t)oc * HW + y * W_ + xx] = cd[f][nf][r] + bias;
            }
        }
}

extern "C" void kernel_launch(void* const* d_in, const int* in_sizes, int n_in,
                              void* d_out, int out_size, void* d_ws, size_t ws_size,
                              hipStream_t stream) {
    (void)in_sizes; (void)n_in; (void)out_size; (void)ws_size;
    const float* x   = (const float*)d_in[0];
    const float* fb  = (const float*)d_in[1];
    const float* ff  = (const float*)d_in[2];
    const float* cw1 = (const float*)d_in[3];
    const float* cb1 = (const float*)d_in[4];
    const float* cw2 = (const float*)d_in[5];
    const float* cb2 = (const float*)d_in[6];
    const float* cw3 = (const float*)d_in[7];
    const float* cb3 = (const float*)d_in[8];
    const float* cw4 = (const float*)d_in[9];
    const float* cb4 = (const float*)d_in[10];
    const float* dw  = (const float*)d_in[11];
    const float* db  = (const float*)d_in[12];
    float* out = (float*)d_out;
    float* ws  = (float*)d_ws;

    // ws layout: bufB (10485760 f32) | cw1t | cw2t | cw3t | w4hi | dwtb | pb4
    float* bufA = out;
    float* bufB = ws;
    float* cw1t = ws + 10485760;
    float* cw2t = cw1t + S1;
    float* cw3t = cw2t + S2;
    ushort* w4hi = (ushort*)(cw3t + S2);       // 294912 ushorts
    ushort* dwtb = w4hi + 294912;              // 49152 ushorts
    float*  pb4  = (float*)(dwtb + 49152);     // 512 f32

    // allow >64KB dynamic LDS (host-side attribute set; not a stream op -> capture-safe)
    (void)hipFuncSetAttribute((const void*)k_dcn5,
                              hipFuncAttributeMaxDynamicSharedMemorySize, LDS_TOT);

    k_prep1<<<(S1 + 2 * S2 + 255) / 256, 256, 0, stream>>>(cw1, cw2, cw3, cw1t, cw2t, cw3t);
    k_prep4<<<1346, 256, 0, stream>>>(cw4, cb4, dw, w4hi, dwtb, pb4);
    k_warp<<<(NP * HW) / 256, 256, 0, stream>>>(x, fb, ff, bufA);
    k_conv<130, 0><<<640, 256, 0, stream>>>(bufA, x, fb, ff, cw1t, cb1, bufB);
    k_conv<64, 1><<<640, 256, 0, stream>>>(bufB, x, fb, ff, cw2t, cb2, bufA);
    k_conv<64, 1><<<640, 256, 0, stream>>>(bufA, x, fb, ff, cw3t, cb3, bufB);

    // zero output frame slots 5 (backward last) and 6 (forward first)
    hipMemsetAsync((char*)d_out + (size_t)5 * C_ * HW * sizeof(float), 0, (size_t)C_ * HW * sizeof(float), stream);
    hipMemsetAsync((char*)d_out + (size_t)6 * C_ * HW * sizeof(float), 0, (size_t)C_ * HW * sizeof(float), stream);

    k_dcn5<<<640, 256, LDS_TOT, stream>>>(bufB, x, fb, ff, w4hi, dwtb, pb4, db, out);
}

// Round 6
// 774.408 us; speedup vs baseline: 2.9001x; 2.2143x over previous
//
#include <hip/hip_runtime.h>
#include <math.h>

#define NP   10
#define C_   64
#define H_   128
#define W_   128
#define HW   (H_*W_)
#define MRM_ 10.0f

// dynamic-LDS layout for k_dcn5 (81408 B -> 2 blocks/CU on 160KB LDS)
#define A_OFF   0u
#define SV_OFF  41472u
#define OMB_OFF 66048u
#define LDS_TOT 81408

// prep section sizes (ushort elems)
#define W1T_N 82944    // 9 chunks * 9 taps * 2 nf * 512
#define W2T_N 36864    // 4 * 9 * 2 * 512
#define W4_N  294912
#define DWT_N 49152

typedef __bf16 bf16x8 __attribute__((ext_vector_type(8)));
typedef float  f32x16 __attribute__((ext_vector_type(16)));

__device__ __forceinline__ f32x16 mfma32(bf16x8 a, bf16x8 b, f32x16 c) {
    return __builtin_amdgcn_mfma_f32_32x32x16_bf16(a, b, c, 0, 0, 0);
}

__device__ __forceinline__ ushort bfrn(float f) {
    uint u = __builtin_bit_cast(uint, f);
    u += 0x7FFFu + ((u >> 16) & 1u);
    return (ushort)(u >> 16);
}
__device__ __forceinline__ float fast_tanh(float x) {
    float e = __expf(2.f * x);
    return 1.f - 2.f / (e + 1.f);
}

// ---------- frame-mapping helpers ----------
__device__ __forceinline__ const float* xi_base(const float* x, int n) {
    int f = (n < 5) ? (n + 1) : (n - 5);
    return x + (size_t)f * C_ * HW;
}
__device__ __forceinline__ const float* cur_base(const float* x, int n) {
    int f = (n < 5) ? n : (n - 4);
    return x + (size_t)f * C_ * HW;
}
__device__ __forceinline__ const float* fl_base(const float* fb, const float* ff, int n) {
    return (n < 5) ? (fb + (size_t)n * 2 * HW) : (ff + (size_t)(n - 5) * 2 * HW);
}

// ---------- bilinear corner helper (zero padding outside) ----------
struct Bil { int i00, i01, i10, i11; float m00, m01, m10, m11; };
__device__ __forceinline__ Bil bil(float py, float px) {
    float y0f = floorf(py), x0f = floorf(px);
    int iy0 = (int)y0f, ix0 = (int)x0f;
    float ay = py - y0f, ax = px - x0f;
    bool v0y = (unsigned)iy0 < (unsigned)H_;
    bool v1y = (unsigned)(iy0 + 1) < (unsigned)H_;
    bool v0x = (unsigned)ix0 < (unsigned)W_;
    bool v1x = (unsigned)(ix0 + 1) < (unsigned)W_;
    int cy0 = min(max(iy0, 0), H_ - 1), cy1 = min(max(iy0 + 1, 0), H_ - 1);
    int cx0 = min(max(ix0, 0), W_ - 1), cx1 = min(max(ix0 + 1, 0), W_ - 1);
    Bil r;
    r.m00 = (1.f - ay) * (1.f - ax) * (float)(v0y && v0x);
    r.m01 = (1.f - ay) * ax         * (float)(v0y && v1x);
    r.m10 = ay * (1.f - ax)         * (float)(v1y && v0x);
    r.m11 = ay * ax                 * (float)(v1y && v1x);
    r.i00 = cy0 * W_ + cx0; r.i01 = cy0 * W_ + cx1;
    r.i10 = cy1 * W_ + cx0; r.i11 = cy1 * W_ + cx1;
    return r;
}

// ---------- MFMA fragment-order weight prep (conv1-4 + dcn + bias) ----------
// frag block layout (all tables): block b = (c*9+t)*2+nf, elem e: l=e>>3, j=e&7,
//   ci = c*16 + (l>>5)*8 + j, oc/ch = nf*32 + (l&31)  (512 elems/block)
__global__ __launch_bounds__(256) void k_prep(
        const float* __restrict__ cw1, const float* __restrict__ cw2,
        const float* __restrict__ cw3, const float* __restrict__ cw4,
        const float* __restrict__ cb4, const float* __restrict__ dw,
        ushort* __restrict__ w1t, ushort* __restrict__ w2t,
        ushort* __restrict__ w3t, ushort* __restrict__ w4t,
        ushort* __restrict__ dwtb, float* __restrict__ pb4) {
    int id = blockIdx.x * 256 + threadIdx.x;
    if (id < W1T_N) {
        int blk = id >> 9, e = id & 511;
        int c = blk / 18, r = blk % 18; int t = r >> 1, nf = r & 1;
        int l = e >> 3, j = e & 7;
        int ci = c * 16 + (l >> 5) * 8 + j;
        int oc = nf * 32 + (l & 31);
        w1t[id] = (ci < 130) ? bfrn(cw1[((size_t)oc * 130 + ci) * 9 + t]) : (ushort)0;
        return;
    }
    id -= W1T_N;
    if (id < W2T_N) {
        int blk = id >> 9, e = id & 511;
        int c = blk / 18, r = blk % 18; int t = r >> 1, nf = r & 1;
        int l = e >> 3, j = e & 7;
        int ci = c * 16 + (l >> 5) * 8 + j;
        int oc = nf * 32 + (l & 31);
        w2t[id] = bfrn(cw2[((size_t)oc * 64 + ci) * 9 + t]);
        return;
    }
    id -= W2T_N;
    if (id < W2T_N) {
        int blk = id >> 9, e = id & 511;
        int c = blk / 18, r = blk % 18; int t = r >> 1, nf = r & 1;
        int l = e >> 3, j = e & 7;
        int ci = c * 16 + (l >> 5) * 8 + j;
        int oc = nf * 32 + (l & 31);
        w3t[id] = bfrn(cw3[((size_t)oc * 64 + ci) * 9 + t]);
        return;
    }
    id -= W2T_N;
    if (id < W4_N) {
        int blk = id >> 9, e = id & 511;
        int c = blk / 144, r = blk - c * 144;
        int t = r >> 4, g = r & 15;
        int l = e >> 3, j = e & 7;
        int nn = l & 31, kh = l >> 5;
        int ci = c * 16 + kh * 8 + j;
        int ch = (nn < 18) ? g * 18 + nn : (nn < 27 ? 288 + g * 9 + (nn - 18) : -1);
        float v = (ch >= 0) ? cw4[((size_t)ch * 64 + ci) * 9 + t] : 0.f;
        w4t[id] = bfrn(v);
        return;
    }
    id -= W4_N;
    if (id < DWT_N) {
        int blk = id >> 9, e = id & 511;
        int g = blk / 6, r = blk - g * 6;
        int kst = r >> 1, nf = r & 1;
        int l = e >> 3, j = e & 7;
        int kk = kst * 16 + (l >> 5) * 8 + j;
        int oc = nf * 32 + (l & 31);
        float v = (kk < 36) ? dw[((size_t)oc * 64 + g * 4 + (kk & 3)) * 9 + (kk >> 2)] : 0.f;
        dwtb[id] = bfrn(v);
        return;
    }
    id -= DWT_N;
    if (id < 512) {
        int g = id >> 5, nn = id & 31;
        int ch = (nn < 18) ? g * 18 + nn : (nn < 27 ? 288 + g * 9 + (nn - 18) : -1);
        pb4[id] = (ch >= 0) ? cb4[ch] : 0.f;
    }
}

// ---------- flow warp (writes bf16 planes) ----------
__global__ __launch_bounds__(256) void k_warp(
        const float* __restrict__ x, const float* __restrict__ fb,
        const float* __restrict__ ff, ushort* __restrict__ warped) {
    int gid = blockIdx.x * 256 + threadIdx.x;
    int n = gid / HW, pos = gid % HW;
    int y = pos / W_, xx = pos % W_;
    const float* fl = fl_base(fb, ff, n);
    float fx = fl[pos], fy = fl[HW + pos];
    Bil b = bil((float)y + fy, (float)xx + fx);
    const float* xb = xi_base(x, n);
    ushort* wout = warped + (size_t)n * C_ * HW + pos;
    for (int c = 0; c < C_; ++c) {
        const float* p = xb + c * HW;
        wout[c * HW] = bfrn(b.m00 * p[b.i00] + b.m01 * p[b.i01]
                          + b.m10 * p[b.i10] + b.m11 * p[b.i11]);
    }
}

// ================== MFMA 3x3 conv, 64 out channels, LeakyReLU, bf16 planes ==================
// 16x16 px tile, 4 waves. Per pass: stage up to 64 ci halo (bf16) -> LDS [cell 324][ci 64]
// (XOR-swizzled, same layout as k_dcn conv4), then 9-tap MFMA sweep.
// SRC==0 (conv1): chunks 0-3 = warped bf16, 4-7 = cur frame f32, 8 = flow f32 + zero pad.
// SRC==1: bf16 input planes [n][64][HW].
template<int NCHUNK, int SRC>
__global__ __launch_bounds__(256, 3) void k_convm(
        const ushort* __restrict__ inb, const float* __restrict__ x,
        const float* __restrict__ fb, const float* __restrict__ ff,
        const ushort* __restrict__ wt, const float* __restrict__ bias,
        ushort* __restrict__ outp) {
    __shared__ __align__(16) char ldsb[41472];
    int tid = threadIdx.x;
    int lane = tid & 63, w = tid >> 6;
    int id = (blockIdx.x & 7) * 80 + (blockIdx.x >> 3);   // bijective XCD swizzle (640%8==0)
    int bx = id & 7, by = (id >> 3) & 7, n = id >> 6;
    int col = lane & 31, khalf = lane >> 5;

    const float* flp = fl_base(fb, ff, n);
    const float* curp = cur_base(x, n);

    f32x16 acc[2][2];
    #pragma unroll
    for (int a = 0; a < 2; ++a)
        #pragma unroll
        for (int b = 0; b < 2; ++b)
            #pragma unroll
            for (int r = 0; r < 16; ++r) acc[a][b][r] = 0.f;

    int xb2 = col & 15;
    int rb0 = 4 * w + ((col >> 4) & 1);
    const int NPASS = (NCHUNK + 3) / 4;

    #pragma unroll
    for (int p = 0; p < NPASS; ++p) {
        const int c0 = 4 * p;
        const int cN = (NCHUNK - c0 >= 4) ? 4 : (NCHUNK - c0);
        __syncthreads();   // previous pass sweep reads done (also fences TBAA reorder)
        // ---- stage cN chunks: thread handles ci = (c0+cc)*16 + w*4 + q
        for (int cc = 0; cc < cN; ++cc) {
            int chunk = c0 + cc;
            int cbase = chunk * 16 + w * 4;
            for (int v = 0; v < 6; ++v) {
                int cell = v * 64 + lane;
                if (cell < 324) {
                    int cy = cell / 18, cx = cell - cy * 18;
                    int gy = by * 16 + cy - 1, gx = bx * 16 + cx - 1;
                    bool ok = ((unsigned)gy < 128u) && ((unsigned)gx < 128u);
                    int pos = gy * W_ + gx;
                    uint2 hv; hv.x = hv.y = 0;
                    if (SRC == 1 || chunk < 4) {
                        const ushort* sp = inb + ((size_t)n * 64 + cbase) * HW + pos;
                        ushort h0 = ok ? sp[0] : (ushort)0;
                        ushort h1 = ok ? sp[HW] : (ushort)0;
                        ushort h2 = ok ? sp[2 * HW] : (ushort)0;
                        ushort h3 = ok ? sp[3 * HW] : (ushort)0;
                        hv.x = (uint)h0 | ((uint)h1 << 16);
                        hv.y = (uint)h2 | ((uint)h3 << 16);
                    } else if (chunk < 8) {
                        const float* sp = curp + (size_t)(cbase - 64) * HW + pos;
                        ushort h0 = bfrn(ok ? sp[0] : 0.f);
                        ushort h1 = bfrn(ok ? sp[HW] : 0.f);
                        ushort h2 = bfrn(ok ? sp[2 * HW] : 0.f);
                        ushort h3 = bfrn(ok ? sp[3 * HW] : 0.f);
                        hv.x = (uint)h0 | ((uint)h1 << 16);
                        hv.y = (uint)h2 | ((uint)h3 << 16);
                    } else {
                        // chunk 8: ci 128,129 = flow; 130..143 = 0 (only w==0 has data)
                        float v0 = 0.f, v1 = 0.f;
                        if (w == 0 && ok) { v0 = flp[pos]; v1 = flp[HW + pos]; }
                        hv.x = (uint)bfrn(v0) | ((uint)bfrn(v1) << 16);
                    }
                    uint byte = (uint)cell * 128 + (uint)cc * 32 + (uint)w * 8;
                    byte ^= ((uint)(cell & 7)) << 4;
                    *(uint2*)(ldsb + byte) = hv;
                }
            }
        }
        __syncthreads();
        // ---- 9-tap MFMA sweep over this pass's chunks
        for (int cc = 0; cc < cN; ++cc) {
            #pragma unroll
            for (int t = 0; t < 9; ++t) {
                const int ky = t / 3, kx = t % 3;
                size_t bb = (size_t)(((c0 + cc) * 9 + t) * 2) * 512 + (size_t)lane * 8;
                bf16x8 b0 = *(const bf16x8*)(wt + bb);
                bf16x8 b1 = *(const bf16x8*)(wt + bb + 512);
                #pragma unroll
                for (int f = 0; f < 2; ++f) {
                    int cell = (rb0 + 2 * f + ky) * 18 + xb2 + kx;
                    uint byte = (uint)cell * 128 + (uint)(2 * cc + khalf) * 16;
                    byte ^= ((uint)(cell & 7)) << 4;
                    bf16x8 a = *(const bf16x8*)(ldsb + byte);
                    acc[f][0] = mfma32(a, b0, acc[f][0]);
                    acc[f][1] = mfma32(a, b1, acc[f][1]);
                }
            }
        }
    }

    // ---- epilogue: bias + LeakyReLU + bf16 store
    ushort* op = outp + (size_t)n * 64 * HW;
    #pragma unroll
    for (int f = 0; f < 2; ++f)
        #pragma unroll
        for (int nf = 0; nf < 2; ++nf) {
            int oc = nf * 32 + col;
            float bs = bias[oc];
            #pragma unroll
            for (int r = 0; r < 16; ++r) {
                int pxl = 64 * w + 32 * f + (r & 3) + 8 * (r >> 2) + 4 * khalf;
                int y = by * 16 + (pxl >> 4), xx = bx * 16 + (pxl & 15);
                float v = acc[f][nf][r] + bs;
                v = (v >= 0.f) ? v : 0.1f * v;
                op[(size_t)oc * HW + y * W_ + xx] = bfrn(v);
            }
        }
}

// ================== fused conv4(bf16 MFMA) + sampler(f32) + DCN GEMM(bf16 MFMA) ==================
// (structure identical to passing round 5; h3 input is now bf16 planes)
__global__ __launch_bounds__(256, 2) void k_dcn5(
        const ushort* __restrict__ h3, const float* __restrict__ x,
        const float* __restrict__ fb, const float* __restrict__ ff,
        const ushort* __restrict__ w4hi,
        const ushort* __restrict__ dwtb, const float* __restrict__ pb4,
        const float* __restrict__ db, float* __restrict__ outb) {
    extern __shared__ __align__(16) char lds[];
    _Float16* OMBH = (_Float16*)(lds + OMB_OFF);   // [px 256][30] f16

    int tid = threadIdx.x;
    int lane = tid & 63, w = tid >> 6;
    int id = (blockIdx.x & 7) * 80 + (blockIdx.x >> 3);
    int bx = id & 7, by = (id >> 3) & 7, n = id >> 6;
    int col = lane & 31, khalf = lane >> 5;

    const ushort* h3n = h3 + (size_t)n * 64 * HW;
    const float* fl = fl_base(fb, ff, n);
    const float* xg0 = xi_base(x, n);

    int Yp = by * 16 + (tid >> 4), Xp = bx * 16 + (tid & 15);
    float fxr = fl[Yp * W_ + Xp];
    float fyr = fl[HW + Yp * W_ + Xp];

    {   // zero sv K-pad slots
        uint pb = SV_OFF + (uint)tid * 96 + 72;
        *(unsigned long long*)(lds + pb)      = 0ull;
        *(unsigned long long*)(lds + pb + 8)  = 0ull;
        *(unsigned long long*)(lds + pb + 16) = 0ull;
    }

    // ---- stage full h3 halo tile: [cell 324][ci 64] bf16, XOR-swizzled
    for (int c = 0; c < 4; ++c) {
        for (int v = 0; v < 6; ++v) {
            int cell = v * 64 + lane;
            if (cell < 324) {
                int cy = cell / 18, cx = cell - cy * 18;
                int gy = by * 16 + cy - 1, gx = bx * 16 + cx - 1;
                bool ok = ((unsigned)gy < 128u) && ((unsigned)gx < 128u);
                const ushort* srcp = h3n + (size_t)(c * 16 + w * 4) * HW + gy * W_ + gx;
                ushort h0 = ok ? srcp[0] : (ushort)0;
                ushort h1 = ok ? srcp[HW] : (ushort)0;
                ushort h2 = ok ? srcp[2 * HW] : (ushort)0;
                ushort h3v = ok ? srcp[3 * HW] : (ushort)0;
                uint2 hv;
                hv.x = (uint)h0 | ((uint)h1 << 16);
                hv.y = (uint)h2 | ((uint)h3v << 16);
                uint byte = (uint)cell * 128 + (uint)c * 32 + (uint)w * 8;
                byte ^= ((uint)(cell & 7)) << 4;
                *(uint2*)(lds + byte) = hv;
            }
        }
    }
    __syncthreads();

    f32x16 zero16;
    #pragma unroll
    for (int r = 0; r < 16; ++r) zero16[r] = 0.f;

    f32x16 cd[2][2];
    #pragma unroll
    for (int a = 0; a < 2; ++a)
        #pragma unroll
        for (int b = 0; b < 2; ++b) cd[a][b] = zero16;

    int xb2 = col & 15;
    int rb0 = 4 * w + ((col >> 4) & 1);

    for (int sp = 0; sp < 8; ++sp) {
        int g0 = sp * 2;
        f32x16 c4[2][2];
        #pragma unroll
        for (int a = 0; a < 2; ++a)
            #pragma unroll
            for (int b = 0; b < 2; ++b) c4[a][b] = zero16;

        #pragma unroll 1
        for (int c = 0; c < 4; ++c) {
            #pragma unroll
            for (int t = 0; t < 9; ++t) {
                const int ky = t / 3, kx = t % 3;
                size_t bb = (size_t)((c * 9 + t) * 16) * 512 + (size_t)lane * 8;
                bf16x8 bh0 = *(const bf16x8*)(w4hi + bb + (size_t)g0 * 512);
                bf16x8 bh1 = *(const bf16x8*)(w4hi + bb + (size_t)(g0 + 1) * 512);
                #pragma unroll
                for (int f = 0; f < 2; ++f) {
                    int cell = (rb0 + 2 * f + ky) * 18 + xb2 + kx;
                    uint byte = (uint)cell * 128 + (uint)(2 * c + khalf) * 16;
                    byte ^= ((uint)(cell & 7)) << 4;
                    bf16x8 ah = *(const bf16x8*)(lds + byte);
                    c4[0][f] = mfma32(ah, bh0, c4[0][f]);
                    c4[1][f] = mfma32(ah, bh1, c4[1][f]);
                }
            }
        }

        #pragma unroll
        for (int gg = 0; gg < 2; ++gg) {
            int g = g0 + gg;
            __syncthreads();
            if (col < 27) {
                float pb = pb4[g * 32 + col];
                #pragma unroll
                for (int f = 0; f < 2; ++f)
                    #pragma unroll
                    for (int r = 0; r < 16; ++r) {
                        int pxl = 64 * w + 32 * f + (r & 3) + 8 * (r >> 2) + 4 * khalf;
                        float v = c4[gg][f][r] + pb;
                        v = (col < 18) ? MRM_ * fast_tanh(v) : 1.f / (1.f + __expf(-v));
                        OMBH[pxl * 30 + col] = (_Float16)v;
                    }
            }
            __syncthreads();
            {
                int px = tid;
                float Yf = (float)Yp, Xf = (float)Xp;
                const float* gb = xg0 + (size_t)(g * 4) * HW;
                #pragma unroll
                for (int k = 0; k < 9; ++k) {
                    float oy = (float)OMBH[px * 30 + 2 * k] + fyr;
                    float ox = (float)OMBH[px * 30 + 2 * k + 1] + fxr;
                    float mk = (float)OMBH[px * 30 + 18 + k];
                    Bil b = bil(Yf - 1.f + (float)(k / 3) + oy,
                                Xf - 1.f + (float)(k % 3) + ox);
                    uint2 pk; pk.x = 0; pk.y = 0;
                    #pragma unroll
                    for (int cc = 0; cc < 4; ++cc) {
                        const float* p = gb + (size_t)cc * HW;
                        float s = (b.m00 * p[b.i00] + b.m01 * p[b.i01]
                                 + b.m10 * p[b.i10] + b.m11 * p[b.i11]) * mk;
                        ushort hv = bfrn(s);
                        if (cc == 0) pk.x |= hv;
                        else if (cc == 1) pk.x |= (uint)hv << 16;
                        else if (cc == 2) pk.y |= hv;
                        else pk.y |= (uint)hv << 16;
                    }
                    *(uint2*)(lds + (SV_OFF + (uint)px * 96 + (uint)k * 8)) = pk;
                }
            }
            __syncthreads();
            #pragma unroll
            for (int kst = 0; kst < 3; ++kst) {
                size_t dbb = (size_t)((g * 3 + kst) * 2) * 512 + (size_t)lane * 8;
                bf16x8 b0 = *(const bf16x8*)(dwtb + dbb);
                bf16x8 b1 = *(const bf16x8*)(dwtb + dbb + 512);
                #pragma unroll
                for (int f = 0; f < 2; ++f) {
                    int pxl = 64 * w + 32 * f + col;
                    uint byte = SV_OFF + (uint)pxl * 96 + (uint)(kst * 2 + khalf) * 16;
                    bf16x8 a = *(const bf16x8*)(lds + byte);
                    cd[f][0] = mfma32(a, b0, cd[f][0]);
                    cd[f][1] = mfma32(a, b1, cd[f][1]);
                }
            }
        }
    }

    float* base = (n < 5) ? outb + (size_t)n * 64 * HW
                          : outb + (size_t)(n + 2) * 64 * HW;
    #pragma unroll
    for (int f = 0; f < 2; ++f)
        #pragma unroll
        for (int nf = 0; nf < 2; ++nf) {
            int oc = nf * 32 + col;
            float bias = db[oc];
            #pragma unroll
            for (int r = 0; r < 16; ++r) {
                int pxl = 64 * w + 32 * f + (r & 3) + 8 * (r >> 2) + 4 * khalf;
                int y = by * 16 + (pxl >> 4), xx = bx * 16 + (pxl & 15);
                base[(size_t)oc * HW + y * W_ + xx] = cd[f][nf][r] + bias;
            }
        }
}

extern "C" void kernel_launch(void* const* d_in, const int* in_sizes, int n_in,
                              void* d_out, int out_size, void* d_ws, size_t ws_size,
                              hipStream_t stream) {
    (void)in_sizes; (void)n_in; (void)out_size; (void)ws_size;
    const float* x   = (const float*)d_in[0];
    const float* fb  = (const float*)d_in[1];
    const float* ff  = (const float*)d_in[2];
    const float* cw1 = (const float*)d_in[3];
    const float* cb1 = (const float*)d_in[4];
    const float* cw2 = (const float*)d_in[5];
    const float* cb2 = (const float*)d_in[6];
    const float* cw3 = (const float*)d_in[7];
    const float* cb3 = (const float*)d_in[8];
    const float* cw4 = (const float*)d_in[9];
    const float* cb4 = (const float*)d_in[10];
    const float* dw  = (const float*)d_in[11];
    const float* db  = (const float*)d_in[12];
    float* out = (float*)d_out;

    // ws: h1(bf16 21MB) | h3(bf16 21MB) | w1t | w2t | w3t | w4t | dwtb | pb4  (~43MB)
    ushort* h1b  = (ushort*)d_ws;
    ushort* h3b  = h1b + 10485760;
    ushort* w1t  = h3b + 10485760;
    ushort* w2t  = w1t + W1T_N;
    ushort* w3t  = w2t + W2T_N;
    ushort* w4t  = w3t + W2T_N;
    ushort* dwtb = w4t + W4_N;
    float*  pb4  = (float*)(dwtb + DWT_N);
    // d_out doubles as scratch: warped(bf16 21MB) | h2(bf16 21MB)  (out is 50.3MB)
    ushort* wpb  = (ushort*)d_out;
    ushort* h2b  = wpb + 10485760;

    (void)hipFuncSetAttribute((const void*)k_dcn5,
                              hipFuncAttributeMaxDynamicSharedMemorySize, LDS_TOT);

    k_prep<<<1958, 256, 0, stream>>>(cw1, cw2, cw3, cw4, cb4, dw,
                                     w1t, w2t, w3t, w4t, dwtb, pb4);
    k_warp<<<(NP * HW) / 256, 256, 0, stream>>>(x, fb, ff, wpb);
    k_convm<9, 0><<<640, 256, 0, stream>>>(wpb, x, fb, ff, w1t, cb1, h1b);
    k_convm<4, 1><<<640, 256, 0, stream>>>(h1b, x, fb, ff, w2t, cb2, h2b);
    k_convm<4, 1><<<640, 256, 0, stream>>>(h2b, x, fb, ff, w3t, cb3, h3b);

    // zero output frame slots 5 (backward last) and 6 (forward first) — after conv3 consumed h2
    hipMemsetAsync((char*)d_out + (size_t)5 * C_ * HW * sizeof(float), 0, (size_t)C_ * HW * sizeof(float), stream);
    hipMemsetAsync((char*)d_out + (size_t)6 * C_ * HW * sizeof(float), 0, (size_t)C_ * HW * sizeof(float), stream);

    k_dcn5<<<640, 256, LDS_TOT, stream>>>(h3b, x, fb, ff, w4t, dwtb, pb4, db, out);
}

// Round 7
// 716.361 us; speedup vs baseline: 3.1350x; 1.0810x over previous
//
#include <hip/hip_runtime.h>
#include <math.h>

#define NP   10
#define C_   64
#define H_   128
#define W_   128
#define HW   (H_*W_)
#define MRM_ 10.0f

// dynamic-LDS layout for k_dcn6 (81408 B -> 2 blocks/CU on 160KB LDS)
#define A_OFF   0u
#define SV_OFF  41472u
#define OMB_OFF 66048u
#define LDS_TOT 81408

// prep section sizes (ushort elems)
#define W1T_N 82944    // 9 chunks * 9 taps * 2 nf * 512
#define W2T_N 36864    // 4 * 9 * 2 * 512
#define W4_N  294912
#define DWT_N 49152

typedef __bf16 bf16x8 __attribute__((ext_vector_type(8)));
typedef float  f32x16 __attribute__((ext_vector_type(16)));

__device__ __forceinline__ f32x16 mfma32(bf16x8 a, bf16x8 b, f32x16 c) {
    return __builtin_amdgcn_mfma_f32_32x32x16_bf16(a, b, c, 0, 0, 0);
}

__device__ __forceinline__ ushort bfrn(float f) {
    uint u = __builtin_bit_cast(uint, f);
    u += 0x7FFFu + ((u >> 16) & 1u);
    return (ushort)(u >> 16);
}
__device__ __forceinline__ float blo(uint u) { return __builtin_bit_cast(float, u << 16); }
__device__ __forceinline__ float bhi(uint u) { return __builtin_bit_cast(float, u & 0xFFFF0000u); }
__device__ __forceinline__ float fast_tanh(float x) {
    float e = __expf(2.f * x);
    return 1.f - 2.f / (e + 1.f);
}

// ---------- frame-mapping helpers ----------
__device__ __forceinline__ const float* xi_base(const float* x, int n) {
    int f = (n < 5) ? (n + 1) : (n - 5);
    return x + (size_t)f * C_ * HW;
}
__device__ __forceinline__ const float* cur_base(const float* x, int n) {
    int f = (n < 5) ? n : (n - 4);
    return x + (size_t)f * C_ * HW;
}
__device__ __forceinline__ const float* fl_base(const float* fb, const float* ff, int n) {
    return (n < 5) ? (fb + (size_t)n * 2 * HW) : (ff + (size_t)(n - 5) * 2 * HW);
}

// ---------- bilinear corner helper (zero padding outside) ----------
struct Bil { int i00, i01, i10, i11; float m00, m01, m10, m11; };
__device__ __forceinline__ Bil bil(float py, float px) {
    float y0f = floorf(py), x0f = floorf(px);
    int iy0 = (int)y0f, ix0 = (int)x0f;
    float ay = py - y0f, ax = px - x0f;
    bool v0y = (unsigned)iy0 < (unsigned)H_;
    bool v1y = (unsigned)(iy0 + 1) < (unsigned)H_;
    bool v0x = (unsigned)ix0 < (unsigned)W_;
    bool v1x = (unsigned)(ix0 + 1) < (unsigned)W_;
    int cy0 = min(max(iy0, 0), H_ - 1), cy1 = min(max(iy0 + 1, 0), H_ - 1);
    int cx0 = min(max(ix0, 0), W_ - 1), cx1 = min(max(ix0 + 1, 0), W_ - 1);
    Bil r;
    r.m00 = (1.f - ay) * (1.f - ax) * (float)(v0y && v0x);
    r.m01 = (1.f - ay) * ax         * (float)(v0y && v1x);
    r.m10 = ay * (1.f - ax)         * (float)(v1y && v0x);
    r.m11 = ay * ax                 * (float)(v1y && v1x);
    r.i00 = cy0 * W_ + cx0; r.i01 = cy0 * W_ + cx1;
    r.i10 = cy1 * W_ + cx0; r.i11 = cy1 * W_ + cx1;
    return r;
}

// ---------- MFMA fragment-order weight prep (conv1-4 + dcn + bias) ----------
__global__ __launch_bounds__(256) void k_prep(
        const float* __restrict__ cw1, const float* __restrict__ cw2,
        const float* __restrict__ cw3, const float* __restrict__ cw4,
        const float* __restrict__ cb4, const float* __restrict__ dw,
        ushort* __restrict__ w1t, ushort* __restrict__ w2t,
        ushort* __restrict__ w3t, ushort* __restrict__ w4t,
        ushort* __restrict__ dwtb, float* __restrict__ pb4) {
    int id = blockIdx.x * 256 + threadIdx.x;
    if (id < W1T_N) {
        int blk = id >> 9, e = id & 511;
        int c = blk / 18, r = blk % 18; int t = r >> 1, nf = r & 1;
        int l = e >> 3, j = e & 7;
        int ci = c * 16 + (l >> 5) * 8 + j;
        int oc = nf * 32 + (l & 31);
        w1t[id] = (ci < 130) ? bfrn(cw1[((size_t)oc * 130 + ci) * 9 + t]) : (ushort)0;
        return;
    }
    id -= W1T_N;
    if (id < W2T_N) {
        int blk = id >> 9, e = id & 511;
        int c = blk / 18, r = blk % 18; int t = r >> 1, nf = r & 1;
        int l = e >> 3, j = e & 7;
        int ci = c * 16 + (l >> 5) * 8 + j;
        int oc = nf * 32 + (l & 31);
        w2t[id] = bfrn(cw2[((size_t)oc * 64 + ci) * 9 + t]);
        return;
    }
    id -= W2T_N;
    if (id < W2T_N) {
        int blk = id >> 9, e = id & 511;
        int c = blk / 18, r = blk % 18; int t = r >> 1, nf = r & 1;
        int l = e >> 3, j = e & 7;
        int ci = c * 16 + (l >> 5) * 8 + j;
        int oc = nf * 32 + (l & 31);
        w3t[id] = bfrn(cw3[((size_t)oc * 64 + ci) * 9 + t]);
        return;
    }
    id -= W2T_N;
    if (id < W4_N) {
        int blk = id >> 9, e = id & 511;
        int c = blk / 144, r = blk - c * 144;
        int t = r >> 4, g = r & 15;
        int l = e >> 3, j = e & 7;
        int nn = l & 31, kh = l >> 5;
        int ci = c * 16 + kh * 8 + j;
        int ch = (nn < 18) ? g * 18 + nn : (nn < 27 ? 288 + g * 9 + (nn - 18) : -1);
        float v = (ch >= 0) ? cw4[((size_t)ch * 64 + ci) * 9 + t] : 0.f;
        w4t[id] = bfrn(v);
        return;
    }
    id -= W4_N;
    if (id < DWT_N) {
        int blk = id >> 9, e = id & 511;
        int g = blk / 6, r = blk - g * 6;
        int kst = r >> 1, nf = r & 1;
        int l = e >> 3, j = e & 7;
        int kk = kst * 16 + (l >> 5) * 8 + j;
        int oc = nf * 32 + (l & 31);
        float v = (kk < 36) ? dw[((size_t)oc * 64 + g * 4 + (kk & 3)) * 9 + (kk >> 2)] : 0.f;
        dwtb[id] = bfrn(v);
        return;
    }
    id -= DWT_N;
    if (id < 512) {
        int g = id >> 5, nn = id & 31;
        int ch = (nn < 18) ? g * 18 + nn : (nn < 27 ? 288 + g * 9 + (nn - 18) : -1);
        pb4[id] = (ch >= 0) ? cb4[ch] : 0.f;
    }
}

// ---------- flow warp (writes bf16 planes) ----------
__global__ __launch_bounds__(256) void k_warp(
        const float* __restrict__ x, const float* __restrict__ fb,
        const float* __restrict__ ff, ushort* __restrict__ warped) {
    int gid = blockIdx.x * 256 + threadIdx.x;
    int n = gid / HW, pos = gid % HW;
    int y = pos / W_, xx = pos % W_;
    const float* fl = fl_base(fb, ff, n);
    float fx = fl[pos], fy = fl[HW + pos];
    Bil b = bil((float)y + fy, (float)xx + fx);
    const float* xb = xi_base(x, n);
    ushort* wout = warped + (size_t)n * C_ * HW + pos;
    for (int c = 0; c < C_; ++c) {
        const float* p = xb + c * HW;
        wout[c * HW] = bfrn(b.m00 * p[b.i00] + b.m01 * p[b.i01]
                          + b.m10 * p[b.i10] + b.m11 * p[b.i11]);
    }
}

// ---------- NCHW f32 -> NHWC bf16 transpose of x frames 0..5 (for the sampler) ----------
__global__ __launch_bounds__(256) void k_xt(
        const float* __restrict__ x, ushort* __restrict__ xt) {
    int gid = blockIdx.x * 256 + threadIdx.x;   // 6*HW threads
    int f = gid / HW, pos = gid % HW;
    const float* src = x + (size_t)f * C_ * HW + pos;
    ushort* dst = xt + ((size_t)f * HW + pos) * 64;
    #pragma unroll
    for (int c8 = 0; c8 < 8; ++c8) {
        uint4 v;
        ushort h0 = bfrn(src[(c8 * 8 + 0) * HW]);
        ushort h1 = bfrn(src[(c8 * 8 + 1) * HW]);
        ushort h2 = bfrn(src[(c8 * 8 + 2) * HW]);
        ushort h3 = bfrn(src[(c8 * 8 + 3) * HW]);
        ushort h4 = bfrn(src[(c8 * 8 + 4) * HW]);
        ushort h5 = bfrn(src[(c8 * 8 + 5) * HW]);
        ushort h6 = bfrn(src[(c8 * 8 + 6) * HW]);
        ushort h7 = bfrn(src[(c8 * 8 + 7) * HW]);
        v.x = (uint)h0 | ((uint)h1 << 16);
        v.y = (uint)h2 | ((uint)h3 << 16);
        v.z = (uint)h4 | ((uint)h5 << 16);
        v.w = (uint)h6 | ((uint)h7 << 16);
        *(uint4*)(dst + c8 * 8) = v;
    }
}

// ================== MFMA 3x3 conv, 64 out channels, LeakyReLU, bf16 planes ==================
template<int NCHUNK, int SRC>
__global__ __launch_bounds__(256, 3) void k_convm(
        const ushort* __restrict__ inb, const float* __restrict__ x,
        const float* __restrict__ fb, const float* __restrict__ ff,
        const ushort* __restrict__ wt, const float* __restrict__ bias,
        ushort* __restrict__ outp) {
    __shared__ __align__(16) char ldsb[41472];
    int tid = threadIdx.x;
    int lane = tid & 63, w = tid >> 6;
    int id = (blockIdx.x & 7) * 80 + (blockIdx.x >> 3);   // bijective XCD swizzle (640%8==0)
    int bx = id & 7, by = (id >> 3) & 7, n = id >> 6;
    int col = lane & 31, khalf = lane >> 5;

    const float* flp = fl_base(fb, ff, n);
    const float* curp = cur_base(x, n);

    f32x16 acc[2][2];
    #pragma unroll
    for (int a = 0; a < 2; ++a)
        #pragma unroll
        for (int b = 0; b < 2; ++b)
            #pragma unroll
            for (int r = 0; r < 16; ++r) acc[a][b][r] = 0.f;

    int xb2 = col & 15;
    int rb0 = 4 * w + ((col >> 4) & 1);
    const int NPASS = (NCHUNK + 3) / 4;

    #pragma unroll
    for (int p = 0; p < NPASS; ++p) {
        const int c0 = 4 * p;
        const int cN = (NCHUNK - c0 >= 4) ? 4 : (NCHUNK - c0);
        __syncthreads();   // previous pass sweep reads done (also fences TBAA reorder)
        for (int cc = 0; cc < cN; ++cc) {
            int chunk = c0 + cc;
            int cbase = chunk * 16 + w * 4;
            for (int v = 0; v < 6; ++v) {
                int cell = v * 64 + lane;
                if (cell < 324) {
                    int cy = cell / 18, cx = cell - cy * 18;
                    int gy = by * 16 + cy - 1, gx = bx * 16 + cx - 1;
                    bool ok = ((unsigned)gy < 128u) && ((unsigned)gx < 128u);
                    int pos = gy * W_ + gx;
                    uint2 hv; hv.x = hv.y = 0;
                    if (SRC == 1 || chunk < 4) {
                        const ushort* sp = inb + ((size_t)n * 64 + cbase) * HW + pos;
                        ushort h0 = ok ? sp[0] : (ushort)0;
                        ushort h1 = ok ? sp[HW] : (ushort)0;
                        ushort h2 = ok ? sp[2 * HW] : (ushort)0;
                        ushort h3 = ok ? sp[3 * HW] : (ushort)0;
                        hv.x = (uint)h0 | ((uint)h1 << 16);
                        hv.y = (uint)h2 | ((uint)h3 << 16);
                    } else if (chunk < 8) {
                        const float* sp = curp + (size_t)(cbase - 64) * HW + pos;
                        ushort h0 = bfrn(ok ? sp[0] : 0.f);
                        ushort h1 = bfrn(ok ? sp[HW] : 0.f);
                        ushort h2 = bfrn(ok ? sp[2 * HW] : 0.f);
                        ushort h3 = bfrn(ok ? sp[3 * HW] : 0.f);
                        hv.x = (uint)h0 | ((uint)h1 << 16);
                        hv.y = (uint)h2 | ((uint)h3 << 16);
                    } else {
                        float v0 = 0.f, v1 = 0.f;
                        if (w == 0 && ok) { v0 = flp[pos]; v1 = flp[HW + pos]; }
                        hv.x = (uint)bfrn(v0) | ((uint)bfrn(v1) << 16);
                    }
                    uint byte = (uint)cell * 128 + (uint)cc * 32 + (uint)w * 8;
                    byte ^= ((uint)(cell & 7)) << 4;
                    *(uint2*)(ldsb + byte) = hv;
                }
            }
        }
        __syncthreads();
        for (int cc = 0; cc < cN; ++cc) {
            #pragma unroll
            for (int t = 0; t < 9; ++t) {
                const int ky = t / 3, kx = t % 3;
                size_t bb = (size_t)(((c0 + cc) * 9 + t) * 2) * 512 + (size_t)lane * 8;
                bf16x8 b0 = *(const bf16x8*)(wt + bb);
                bf16x8 b1 = *(const bf16x8*)(wt + bb + 512);
                #pragma unroll
                for (int f = 0; f < 2; ++f) {
                    int cell = (rb0 + 2 * f + ky) * 18 + xb2 + kx;
                    uint byte = (uint)cell * 128 + (uint)(2 * cc + khalf) * 16;
                    byte ^= ((uint)(cell & 7)) << 4;
                    bf16x8 a = *(const bf16x8*)(ldsb + byte);
                    acc[f][0] = mfma32(a, b0, acc[f][0]);
                    acc[f][1] = mfma32(a, b1, acc[f][1]);
                }
            }
        }
    }

    ushort* op = outp + (size_t)n * 64 * HW;
    #pragma unroll
    for (int f = 0; f < 2; ++f)
        #pragma unroll
        for (int nf = 0; nf < 2; ++nf) {
            int oc = nf * 32 + col;
            float bs = bias[oc];
            #pragma unroll
            for (int r = 0; r < 16; ++r) {
                int pxl = 64 * w + 32 * f + (r & 3) + 8 * (r >> 2) + 4 * khalf;
                int y = by * 16 + (pxl >> 4), xx = bx * 16 + (pxl & 15);
                float v = acc[f][nf][r] + bs;
                v = (v >= 0.f) ? v : 0.1f * v;
                op[(size_t)oc * HW + y * W_ + xx] = bfrn(v);
            }
        }
}

// ================== fused conv4(bf16 MFMA) + sampler(NHWC bf16) + DCN GEMM(bf16 MFMA) ==================
// (structure identical to passing round 6; sampler reads NHWC-bf16 x_t: 4 corner loads/tap not 16)
__global__ __launch_bounds__(256, 2) void k_dcn6(
        const ushort* __restrict__ h3, const ushort* __restrict__ xt,
        const float* __restrict__ fb, const float* __restrict__ ff,
        const ushort* __restrict__ w4hi,
        const ushort* __restrict__ dwtb, const float* __restrict__ pb4,
        const float* __restrict__ db, float* __restrict__ outb) {
    extern __shared__ __align__(16) char lds[];
    _Float16* OMBH = (_Float16*)(lds + OMB_OFF);   // [px 256][30] f16

    int tid = threadIdx.x;
    int lane = tid & 63, w = tid >> 6;
    int id = (blockIdx.x & 7) * 80 + (blockIdx.x >> 3);
    int bx = id & 7, by = (id >> 3) & 7, n = id >> 6;
    int col = lane & 31, khalf = lane >> 5;

    const ushort* h3n = h3 + (size_t)n * 64 * HW;
    const float* fl = fl_base(fb, ff, n);
    int fxi = (n < 5) ? (n + 1) : (n - 5);
    const ushort* xtn = xt + (size_t)fxi * HW * 64;

    int Yp = by * 16 + (tid >> 4), Xp = bx * 16 + (tid & 15);
    float fxr = fl[Yp * W_ + Xp];
    float fyr = fl[HW + Yp * W_ + Xp];

    {   // zero sv K-pad slots
        uint pb = SV_OFF + (uint)tid * 96 + 72;
        *(unsigned long long*)(lds + pb)      = 0ull;
        *(unsigned long long*)(lds + pb + 8)  = 0ull;
        *(unsigned long long*)(lds + pb + 16) = 0ull;
    }

    // ---- stage full h3 halo tile: [cell 324][ci 64] bf16, XOR-swizzled
    for (int c = 0; c < 4; ++c) {
        for (int v = 0; v < 6; ++v) {
            int cell = v * 64 + lane;
            if (cell < 324) {
                int cy = cell / 18, cx = cell - cy * 18;
                int gy = by * 16 + cy - 1, gx = bx * 16 + cx - 1;
                bool ok = ((unsigned)gy < 128u) && ((unsigned)gx < 128u);
                const ushort* srcp = h3n + (size_t)(c * 16 + w * 4) * HW + gy * W_ + gx;
                ushort h0 = ok ? srcp[0] : (ushort)0;
                ushort h1 = ok ? srcp[HW] : (ushort)0;
                ushort h2 = ok ? srcp[2 * HW] : (ushort)0;
                ushort h3v = ok ? srcp[3 * HW] : (ushort)0;
                uint2 hv;
                hv.x = (uint)h0 | ((uint)h1 << 16);
                hv.y = (uint)h2 | ((uint)h3v << 16);
                uint byte = (uint)cell * 128 + (uint)c * 32 + (uint)w * 8;
                byte ^= ((uint)(cell & 7)) << 4;
                *(uint2*)(lds + byte) = hv;
            }
        }
    }
    __syncthreads();

    f32x16 zero16;
    #pragma unroll
    for (int r = 0; r < 16; ++r) zero16[r] = 0.f;

    f32x16 cd[2][2];
    #pragma unroll
    for (int a = 0; a < 2; ++a)
        #pragma unroll
        for (int b = 0; b < 2; ++b) cd[a][b] = zero16;

    int xb2 = col & 15;
    int rb0 = 4 * w + ((col >> 4) & 1);

    for (int sp = 0; sp < 8; ++sp) {
        int g0 = sp * 2;
        f32x16 c4[2][2];
        #pragma unroll
        for (int a = 0; a < 2; ++a)
            #pragma unroll
            for (int b = 0; b < 2; ++b) c4[a][b] = zero16;

        #pragma unroll 1
        for (int c = 0; c < 4; ++c) {
            #pragma unroll
            for (int t = 0; t < 9; ++t) {
                const int ky = t / 3, kx = t % 3;
                size_t bb = (size_t)((c * 9 + t) * 16) * 512 + (size_t)lane * 8;
                bf16x8 bh0 = *(const bf16x8*)(w4hi + bb + (size_t)g0 * 512);
                bf16x8 bh1 = *(const bf16x8*)(w4hi + bb + (size_t)(g0 + 1) * 512);
                #pragma unroll
                for (int f = 0; f < 2; ++f) {
                    int cell = (rb0 + 2 * f + ky) * 18 + xb2 + kx;
                    uint byte = (uint)cell * 128 + (uint)(2 * c + khalf) * 16;
                    byte ^= ((uint)(cell & 7)) << 4;
                    bf16x8 ah = *(const bf16x8*)(lds + byte);
                    c4[0][f] = mfma32(ah, bh0, c4[0][f]);
                    c4[1][f] = mfma32(ah, bh1, c4[1][f]);
                }
            }
        }

        #pragma unroll
        for (int gg = 0; gg < 2; ++gg) {
            int g = g0 + gg;
            __syncthreads();   // prev gemm sv/omb reads done; fence vs following writes
            if (col < 27) {
                float pb = pb4[g * 32 + col];
                #pragma unroll
                for (int f = 0; f < 2; ++f)
                    #pragma unroll
                    for (int r = 0; r < 16; ++r) {
                        int pxl = 64 * w + 32 * f + (r & 3) + 8 * (r >> 2) + 4 * khalf;
                        float v = c4[gg][f][r] + pb;
                        v = (col < 18) ? MRM_ * fast_tanh(v) : 1.f / (1.f + __expf(-v));
                        OMBH[pxl * 30 + col] = (_Float16)v;
                    }
            }
            __syncthreads();   // om visible
            // ---- sampler: 1 px per thread; NHWC bf16 -> 4 corner loads/tap (uint2 = 4 ch)
            {
                int px = tid;
                float Yf = (float)Yp, Xf = (float)Xp;
                const uint gof = (uint)g * 4;
                #pragma unroll
                for (int k = 0; k < 9; ++k) {
                    float oy = (float)OMBH[px * 30 + 2 * k] + fyr;
                    float ox = (float)OMBH[px * 30 + 2 * k + 1] + fxr;
                    float mk = (float)OMBH[px * 30 + 18 + k];
                    Bil b = bil(Yf - 1.f + (float)(k / 3) + oy,
                                Xf - 1.f + (float)(k % 3) + ox);
                    uint2 q00 = *(const uint2*)(xtn + (size_t)b.i00 * 64 + gof);
                    uint2 q01 = *(const uint2*)(xtn + (size_t)b.i01 * 64 + gof);
                    uint2 q10 = *(const uint2*)(xtn + (size_t)b.i10 * 64 + gof);
                    uint2 q11 = *(const uint2*)(xtn + (size_t)b.i11 * 64 + gof);
                    float s0 = b.m00 * blo(q00.x) + b.m01 * blo(q01.x)
                             + b.m10 * blo(q10.x) + b.m11 * blo(q11.x);
                    float s1 = b.m00 * bhi(q00.x) + b.m01 * bhi(q01.x)
                             + b.m10 * bhi(q10.x) + b.m11 * bhi(q11.x);
                    float s2 = b.m00 * blo(q00.y) + b.m01 * blo(q01.y)
                             + b.m10 * blo(q10.y) + b.m11 * blo(q11.y);
                    float s3 = b.m00 * bhi(q00.y) + b.m01 * bhi(q01.y)
                             + b.m10 * bhi(q10.y) + b.m11 * bhi(q11.y);
                    uint2 pk;
                    pk.x = (uint)bfrn(s0 * mk) | ((uint)bfrn(s1 * mk) << 16);
                    pk.y = (uint)bfrn(s2 * mk) | ((uint)bfrn(s3 * mk) << 16);
                    *(uint2*)(lds + (SV_OFF + (uint)px * 96 + (uint)k * 8)) = pk;
                }
            }
            __syncthreads();   // sv visible (and fences uint2 stores vs bf16x8 loads)
            #pragma unroll
            for (int kst = 0; kst < 3; ++kst) {
                size_t dbb = (size_t)((g * 3 + kst) * 2) * 512 + (size_t)lane * 8;
                bf16x8 b0 = *(const bf16x8*)(dwtb + dbb);
                bf16x8 b1 = *(const bf16x8*)(dwtb + dbb + 512);
                #pragma unroll
                for (int f = 0; f < 2; ++f) {
                    int pxl = 64 * w + 32 * f + col;
                    uint byte = SV_OFF + (uint)pxl * 96 + (uint)(kst * 2 + khalf) * 16;
                    bf16x8 a = *(const bf16x8*)(lds + byte);
                    cd[f][0] = mfma32(a, b0, cd[f][0]);
                    cd[f][1] = mfma32(a, b1, cd[f][1]);
                }
            }
        }
    }

    float* base = (n < 5) ? outb + (size_t)n * 64 * HW
                          : outb + (size_t)(n + 2) * 64 * HW;
    #pragma unroll
    for (int f = 0; f < 2; ++f)
        #pragma unroll
        for (int nf = 0; nf < 2; ++nf) {
            int oc = nf * 32 + col;
            float bias = db[oc];
            #pragma unroll
            for (int r = 0; r < 16; ++r) {
                int pxl = 64 * w + 32 * f + (r & 3) + 8 * (r >> 2) + 4 * khalf;
                int y = by * 16 + (pxl >> 4), xx = bx * 16 + (pxl & 15);
                base[(size_t)oc * HW + y * W_ + xx] = cd[f][nf][r] + bias;
            }
        }
}

extern "C" void kernel_launch(void* const* d_in, const int* in_sizes, int n_in,
                              void* d_out, int out_size, void* d_ws, size_t ws_size,
                              hipStream_t stream) {
    (void)in_sizes; (void)n_in; (void)out_size; (void)ws_size;
    const float* x   = (const float*)d_in[0];
    const float* fb  = (const float*)d_in[1];
    const float* ff  = (const float*)d_in[2];
    const float* cw1 = (const float*)d_in[3];
    const float* cb1 = (const float*)d_in[4];
    const float* cw2 = (const float*)d_in[5];
    const float* cb2 = (const float*)d_in[6];
    const float* cw3 = (const float*)d_in[7];
    const float* cb3 = (const float*)d_in[8];
    const float* cw4 = (const float*)d_in[9];
    const float* cb4 = (const float*)d_in[10];
    const float* dw  = (const float*)d_in[11];
    const float* db  = (const float*)d_in[12];
    float* out = (float*)d_out;

    // ws: h1(bf16 21MB, later reused as x_t NHWC) | h3(bf16 21MB) | w1t | w2t | w3t | w4t | dwtb | pb4
    ushort* h1b  = (ushort*)d_ws;
    ushort* h3b  = h1b + 10485760;
    ushort* w1t  = h3b + 10485760;
    ushort* w2t  = w1t + W1T_N;
    ushort* w3t  = w2t + W2T_N;
    ushort* w4t  = w3t + W2T_N;
    ushort* dwtb = w4t + W4_N;
    float*  pb4  = (float*)(dwtb + DWT_N);
    ushort* xtb  = h1b;   // x_t overlays h1 (h1 dead after conv2; k_xt launches after conv2)
    // d_out doubles as scratch: warped(bf16 21MB) | h2(bf16 21MB)
    ushort* wpb  = (ushort*)d_out;
    ushort* h2b  = wpb + 10485760;

    (void)hipFuncSetAttribute((const void*)k_dcn6,
                              hipFuncAttributeMaxDynamicSharedMemorySize, LDS_TOT);

    k_prep<<<1958, 256, 0, stream>>>(cw1, cw2, cw3, cw4, cb4, dw,
                                     w1t, w2t, w3t, w4t, dwtb, pb4);
    k_warp<<<(NP * HW) / 256, 256, 0, stream>>>(x, fb, ff, wpb);
    k_convm<9, 0><<<640, 256, 0, stream>>>(wpb, x, fb, ff, w1t, cb1, h1b);
    k_convm<4, 1><<<640, 256, 0, stream>>>(h1b, x, fb, ff, w2t, cb2, h2b);
    k_xt<<<(6 * HW) / 256, 256, 0, stream>>>(x, xtb);   // after conv2 (h1 dead), before k_dcn
    k_convm<4, 1><<<640, 256, 0, stream>>>(h2b, x, fb, ff, w3t, cb3, h3b);

    // zero output frame slots 5 (backward last) and 6 (forward first) — after conv3 consumed h2
    hipMemsetAsync((char*)d_out + (size_t)5 * C_ * HW * sizeof(float), 0, (size_t)C_ * HW * sizeof(float), stream);
    hipMemsetAsync((char*)d_out + (size_t)6 * C_ * HW * sizeof(float), 0, (size_t)C_ * HW * sizeof(float), stream);

    k_dcn6<<<640, 256, LDS_TOT, stream>>>(h3b, xtb, fb, ff, w4t, dwtb, pb4, db, out);
}

// Round 8
// 618.093 us; speedup vs baseline: 3.6335x; 1.1590x over previous
//
#include <hip/hip_runtime.h>
#include <math.h>

#define NP   10
#define C_   64
#define H_   128
#define W_   128
#define HW   (H_*W_)
#define MRM_ 10.0f

// dynamic-LDS layout for k_dcn7 (81408 B -> 2 blocks/CU on 160KB LDS)
#define A_OFF   0u
#define SV_OFF  41472u
#define OMB_OFF 66048u
#define LDS_TOT 81408

// prep section sizes (ushort elems)
#define W1T_N 82944    // 9 chunks * 9 taps * 2 nf * 512
#define W2T_N 36864    // 4 * 9 * 2 * 512
#define W4_N  294912
#define DWT_N 49152

typedef __bf16 bf16x8 __attribute__((ext_vector_type(8)));
typedef float  f32x16 __attribute__((ext_vector_type(16)));

__device__ __forceinline__ f32x16 mfma32(bf16x8 a, bf16x8 b, f32x16 c) {
    return __builtin_amdgcn_mfma_f32_32x32x16_bf16(a, b, c, 0, 0, 0);
}

__device__ __forceinline__ ushort bfrn(float f) {
    uint u = __builtin_bit_cast(uint, f);
    u += 0x7FFFu + ((u >> 16) & 1u);
    return (ushort)(u >> 16);
}
__device__ __forceinline__ float blo(uint u) { return __builtin_bit_cast(float, u << 16); }
__device__ __forceinline__ float bhi(uint u) { return __builtin_bit_cast(float, u & 0xFFFF0000u); }
__device__ __forceinline__ float fast_tanh(float x) {
    float e = __expf(2.f * x);
    return 1.f - 2.f / (e + 1.f);
}

// ---------- frame-mapping helpers ----------
__device__ __forceinline__ const float* xi_base(const float* x, int n) {
    int f = (n < 5) ? (n + 1) : (n - 5);
    return x + (size_t)f * C_ * HW;
}
__device__ __forceinline__ const float* cur_base(const float* x, int n) {
    int f = (n < 5) ? n : (n - 4);
    return x + (size_t)f * C_ * HW;
}
__device__ __forceinline__ const float* fl_base(const float* fb, const float* ff, int n) {
    return (n < 5) ? (fb + (size_t)n * 2 * HW) : (ff + (size_t)(n - 5) * 2 * HW);
}

// ---------- bilinear corner helper (zero padding outside) ----------
struct Bil { int i00, i01, i10, i11; float m00, m01, m10, m11; };
__device__ __forceinline__ Bil bil(float py, float px) {
    float y0f = floorf(py), x0f = floorf(px);
    int iy0 = (int)y0f, ix0 = (int)x0f;
    float ay = py - y0f, ax = px - x0f;
    bool v0y = (unsigned)iy0 < (unsigned)H_;
    bool v1y = (unsigned)(iy0 + 1) < (unsigned)H_;
    bool v0x = (unsigned)ix0 < (unsigned)W_;
    bool v1x = (unsigned)(ix0 + 1) < (unsigned)W_;
    int cy0 = min(max(iy0, 0), H_ - 1), cy1 = min(max(iy0 + 1, 0), H_ - 1);
    int cx0 = min(max(ix0, 0), W_ - 1), cx1 = min(max(ix0 + 1, 0), W_ - 1);
    Bil r;
    r.m00 = (1.f - ay) * (1.f - ax) * (float)(v0y && v0x);
    r.m01 = (1.f - ay) * ax         * (float)(v0y && v1x);
    r.m10 = ay * (1.f - ax)         * (float)(v1y && v0x);
    r.m11 = ay * ax                 * (float)(v1y && v1x);
    r.i00 = cy0 * W_ + cx0; r.i01 = cy0 * W_ + cx1;
    r.i10 = cy1 * W_ + cx0; r.i11 = cy1 * W_ + cx1;
    return r;
}

// ---------- MFMA fragment-order weight prep (conv1-4 + dcn + bias) ----------
__global__ __launch_bounds__(256) void k_prep(
        const float* __restrict__ cw1, const float* __restrict__ cw2,
        const float* __restrict__ cw3, const float* __restrict__ cw4,
        const float* __restrict__ cb4, const float* __restrict__ dw,
        ushort* __restrict__ w1t, ushort* __restrict__ w2t,
        ushort* __restrict__ w3t, ushort* __restrict__ w4t,
        ushort* __restrict__ dwtb, float* __restrict__ pb4) {
    int id = blockIdx.x * 256 + threadIdx.x;
    if (id < W1T_N) {
        int blk = id >> 9, e = id & 511;
        int c = blk / 18, r = blk % 18; int t = r >> 1, nf = r & 1;
        int l = e >> 3, j = e & 7;
        int ci = c * 16 + (l >> 5) * 8 + j;
        int oc = nf * 32 + (l & 31);
        w1t[id] = (ci < 130) ? bfrn(cw1[((size_t)oc * 130 + ci) * 9 + t]) : (ushort)0;
        return;
    }
    id -= W1T_N;
    if (id < W2T_N) {
        int blk = id >> 9, e = id & 511;
        int c = blk / 18, r = blk % 18; int t = r >> 1, nf = r & 1;
        int l = e >> 3, j = e & 7;
        int ci = c * 16 + (l >> 5) * 8 + j;
        int oc = nf * 32 + (l & 31);
        w2t[id] = bfrn(cw2[((size_t)oc * 64 + ci) * 9 + t]);
        return;
    }
    id -= W2T_N;
    if (id < W2T_N) {
        int blk = id >> 9, e = id & 511;
        int c = blk / 18, r = blk % 18; int t = r >> 1, nf = r & 1;
        int l = e >> 3, j = e & 7;
        int ci = c * 16 + (l >> 5) * 8 + j;
        int oc = nf * 32 + (l & 31);
        w3t[id] = bfrn(cw3[((size_t)oc * 64 + ci) * 9 + t]);
        return;
    }
    id -= W2T_N;
    if (id < W4_N) {
        int blk = id >> 9, e = id & 511;
        int c = blk / 144, r = blk - c * 144;
        int t = r >> 4, g = r & 15;
        int l = e >> 3, j = e & 7;
        int nn = l & 31, kh = l >> 5;
        int ci = c * 16 + kh * 8 + j;
        int ch = (nn < 18) ? g * 18 + nn : (nn < 27 ? 288 + g * 9 + (nn - 18) : -1);
        float v = (ch >= 0) ? cw4[((size_t)ch * 64 + ci) * 9 + t] : 0.f;
        w4t[id] = bfrn(v);
        return;
    }
    id -= W4_N;
    if (id < DWT_N) {
        int blk = id >> 9, e = id & 511;
        int g = blk / 6, r = blk - g * 6;
        int kst = r >> 1, nf = r & 1;
        int l = e >> 3, j = e & 7;
        int kk = kst * 16 + (l >> 5) * 8 + j;
        int oc = nf * 32 + (l & 31);
        float v = (kk < 36) ? dw[((size_t)oc * 64 + g * 4 + (kk & 3)) * 9 + (kk >> 2)] : 0.f;
        dwtb[id] = bfrn(v);
        return;
    }
    id -= DWT_N;
    if (id < 512) {
        int g = id >> 5, nn = id & 31;
        int ch = (nn < 18) ? g * 18 + nn : (nn < 27 ? 288 + g * 9 + (nn - 18) : -1);
        pb4[id] = (ch >= 0) ? cb4[ch] : 0.f;
    }
}

// ---------- flow warp (writes bf16 planes) ----------
__global__ __launch_bounds__(256) void k_warp(
        const float* __restrict__ x, const float* __restrict__ fb,
        const float* __restrict__ ff, ushort* __restrict__ warped) {
    int gid = blockIdx.x * 256 + threadIdx.x;
    int n = gid / HW, pos = gid % HW;
    int y = pos / W_, xx = pos % W_;
    const float* fl = fl_base(fb, ff, n);
    float fx = fl[pos], fy = fl[HW + pos];
    Bil b = bil((float)y + fy, (float)xx + fx);
    const float* xb = xi_base(x, n);
    ushort* wout = warped + (size_t)n * C_ * HW + pos;
    for (int c = 0; c < C_; ++c) {
        const float* p = xb + c * HW;
        wout[c * HW] = bfrn(b.m00 * p[b.i00] + b.m01 * p[b.i01]
                          + b.m10 * p[b.i10] + b.m11 * p[b.i11]);
    }
}

// ---------- NCHW f32 -> per-GROUP NHWC bf16: xt[f][g][HW][4ch] ----------
// pixel stride = 8B so x-adjacent lanes of a sampler gather share cache lines
// ([px][64ch] had 128B px stride: every lane a distinct line -> L1-BW-bound, r7 lesson).
__global__ __launch_bounds__(256) void k_xt(
        const float* __restrict__ x, ushort* __restrict__ xt) {
    int gid = blockIdx.x * 256 + threadIdx.x;   // 6*HW threads
    int f = gid / HW, pos = gid % HW;
    const float* src = x + (size_t)f * C_ * HW + pos;
    ushort* dst = xt + (size_t)f * 16 * HW * 4;
    #pragma unroll
    for (int g = 0; g < 16; ++g) {
        uint2 v;
        ushort h0 = bfrn(src[(g * 4 + 0) * HW]);
        ushort h1 = bfrn(src[(g * 4 + 1) * HW]);
        ushort h2 = bfrn(src[(g * 4 + 2) * HW]);
        ushort h3 = bfrn(src[(g * 4 + 3) * HW]);
        v.x = (uint)h0 | ((uint)h1 << 16);
        v.y = (uint)h2 | ((uint)h3 << 16);
        *(uint2*)(dst + ((size_t)g * HW + pos) * 4) = v;
    }
}

// ================== MFMA 3x3 conv, 64 out channels, LeakyReLU, bf16 planes ==================
template<int NCHUNK, int SRC>
__global__ __launch_bounds__(256, 3) void k_convm(
        const ushort* __restrict__ inb, const float* __restrict__ x,
        const float* __restrict__ fb, const float* __restrict__ ff,
        const ushort* __restrict__ wt, const float* __restrict__ bias,
        ushort* __restrict__ outp) {
    __shared__ __align__(16) char ldsb[41472];
    int tid = threadIdx.x;
    int lane = tid & 63, w = tid >> 6;
    int id = (blockIdx.x & 7) * 80 + (blockIdx.x >> 3);   // bijective XCD swizzle (640%8==0)
    int bx = id & 7, by = (id >> 3) & 7, n = id >> 6;
    int col = lane & 31, khalf = lane >> 5;

    const float* flp = fl_base(fb, ff, n);
    const float* curp = cur_base(x, n);

    f32x16 acc[2][2];
    #pragma unroll
    for (int a = 0; a < 2; ++a)
        #pragma unroll
        for (int b = 0; b < 2; ++b)
            #pragma unroll
            for (int r = 0; r < 16; ++r) acc[a][b][r] = 0.f;

    int xb2 = col & 15;
    int rb0 = 4 * w + ((col >> 4) & 1);
    const int NPASS = (NCHUNK + 3) / 4;

    #pragma unroll
    for (int p = 0; p < NPASS; ++p) {
        const int c0 = 4 * p;
        const int cN = (NCHUNK - c0 >= 4) ? 4 : (NCHUNK - c0);
        __syncthreads();   // previous pass sweep reads done (also fences TBAA reorder)
        for (int cc = 0; cc < cN; ++cc) {
            int chunk = c0 + cc;
            int cbase = chunk * 16 + w * 4;
            for (int v = 0; v < 6; ++v) {
                int cell = v * 64 + lane;
                if (cell < 324) {
                    int cy = cell / 18, cx = cell - cy * 18;
                    int gy = by * 16 + cy - 1, gx = bx * 16 + cx - 1;
                    bool ok = ((unsigned)gy < 128u) && ((unsigned)gx < 128u);
                    int pos = gy * W_ + gx;
                    uint2 hv; hv.x = hv.y = 0;
                    if (SRC == 1 || chunk < 4) {
                        const ushort* sp = inb + ((size_t)n * 64 + cbase) * HW + pos;
                        ushort h0 = ok ? sp[0] : (ushort)0;
                        ushort h1 = ok ? sp[HW] : (ushort)0;
                        ushort h2 = ok ? sp[2 * HW] : (ushort)0;
                        ushort h3 = ok ? sp[3 * HW] : (ushort)0;
                        hv.x = (uint)h0 | ((uint)h1 << 16);
                        hv.y = (uint)h2 | ((uint)h3 << 16);
                    } else if (chunk < 8) {
                        const float* sp = curp + (size_t)(cbase - 64) * HW + pos;
                        ushort h0 = bfrn(ok ? sp[0] : 0.f);
                        ushort h1 = bfrn(ok ? sp[HW] : 0.f);
                        ushort h2 = bfrn(ok ? sp[2 * HW] : 0.f);
                        ushort h3 = bfrn(ok ? sp[3 * HW] : 0.f);
                        hv.x = (uint)h0 | ((uint)h1 << 16);
                        hv.y = (uint)h2 | ((uint)h3 << 16);
                    } else {
                        float v0 = 0.f, v1 = 0.f;
                        if (w == 0 && ok) { v0 = flp[pos]; v1 = flp[HW + pos]; }
                        hv.x = (uint)bfrn(v0) | ((uint)bfrn(v1) << 16);
                    }
                    uint byte = (uint)cell * 128 + (uint)cc * 32 + (uint)w * 8;
                    byte ^= ((uint)(cell & 7)) << 4;
                    *(uint2*)(ldsb + byte) = hv;
                }
            }
        }
        __syncthreads();
        for (int cc = 0; cc < cN; ++cc) {
            #pragma unroll
            for (int t = 0; t < 9; ++t) {
                const int ky = t / 3, kx = t % 3;
                size_t bb = (size_t)(((c0 + cc) * 9 + t) * 2) * 512 + (size_t)lane * 8;
                bf16x8 b0 = *(const bf16x8*)(wt + bb);
                bf16x8 b1 = *(const bf16x8*)(wt + bb + 512);
                #pragma unroll
                for (int f = 0; f < 2; ++f) {
                    int cell = (rb0 + 2 * f + ky) * 18 + xb2 + kx;
                    uint byte = (uint)cell * 128 + (uint)(2 * cc + khalf) * 16;
                    byte ^= ((uint)(cell & 7)) << 4;
                    bf16x8 a = *(const bf16x8*)(ldsb + byte);
                    acc[f][0] = mfma32(a, b0, acc[f][0]);
                    acc[f][1] = mfma32(a, b1, acc[f][1]);
                }
            }
        }
    }

    ushort* op = outp + (size_t)n * 64 * HW;
    #pragma unroll
    for (int f = 0; f < 2; ++f)
        #pragma unroll
        for (int nf = 0; nf < 2; ++nf) {
            int oc = nf * 32 + col;
            float bs = bias[oc];
            #pragma unroll
            for (int r = 0; r < 16; ++r) {
                int pxl = 64 * w + 32 * f + (r & 3) + 8 * (r >> 2) + 4 * khalf;
                int y = by * 16 + (pxl >> 4), xx = bx * 16 + (pxl & 15);
                float v = acc[f][nf][r] + bs;
                v = (v >= 0.f) ? v : 0.1f * v;
                op[(size_t)oc * HW + y * W_ + xx] = bfrn(v);
            }
        }
}

// ================== fused conv4(bf16 MFMA) + sampler(group-NHWC) + DCN GEMM(bf16 MFMA) ==================
// Inner-loop LDS (OMB, sv) is WAVE-PRIVATE (writer rows == reader rows == [64w,64w+64));
// only the A-tile is cross-wave and it is read-only after the one staging barrier.
// So the inner phase boundaries need only COMPILE-TIME fences (sched_barrier(0)) to stop
// TBAA reordering (round-3 lesson: uint2 stores vs bf16x8 loads "don't alias"); hardware
// DS ops from one wave execute in order. No s_barrier -> no 4-wave convoy, waves drift.
__global__ __launch_bounds__(256, 2) void k_dcn7(
        const ushort* __restrict__ h3, const ushort* __restrict__ xt,
        const float* __restrict__ fb, const float* __restrict__ ff,
        const ushort* __restrict__ w4hi,
        const ushort* __restrict__ dwtb, const float* __restrict__ pb4,
        const float* __restrict__ db, float* __restrict__ outb) {
    extern __shared__ __align__(16) char lds[];
    _Float16* OMBH = (_Float16*)(lds + OMB_OFF);   // [px 256][30] f16

    int tid = threadIdx.x;
    int lane = tid & 63, w = tid >> 6;
    int id = (blockIdx.x & 7) * 80 + (blockIdx.x >> 3);
    int bx = id & 7, by = (id >> 3) & 7, n = id >> 6;
    int col = lane & 31, khalf = lane >> 5;

    const ushort* h3n = h3 + (size_t)n * 64 * HW;
    const float* fl = fl_base(fb, ff, n);
    int fxi = (n < 5) ? (n + 1) : (n - 5);
    const ushort* xtn = xt + (size_t)fxi * 16 * HW * 4;

    int Yp = by * 16 + (tid >> 4), Xp = bx * 16 + (tid & 15);
    float fxr = fl[Yp * W_ + Xp];
    float fyr = fl[HW + Yp * W_ + Xp];

    {   // zero sv K-pad slots
        uint pb = SV_OFF + (uint)tid * 96 + 72;
        *(unsigned long long*)(lds + pb)      = 0ull;
        *(unsigned long long*)(lds + pb + 8)  = 0ull;
        *(unsigned long long*)(lds + pb + 16) = 0ull;
    }

    // ---- stage full h3 halo tile: [cell 324][ci 64] bf16, XOR-swizzled
    for (int c = 0; c < 4; ++c) {
        for (int v = 0; v < 6; ++v) {
            int cell = v * 64 + lane;
            if (cell < 324) {
                int cy = cell / 18, cx = cell - cy * 18;
                int gy = by * 16 + cy - 1, gx = bx * 16 + cx - 1;
                bool ok = ((unsigned)gy < 128u) && ((unsigned)gx < 128u);
                const ushort* srcp = h3n + (size_t)(c * 16 + w * 4) * HW + gy * W_ + gx;
                ushort h0 = ok ? srcp[0] : (ushort)0;
                ushort h1 = ok ? srcp[HW] : (ushort)0;
                ushort h2 = ok ? srcp[2 * HW] : (ushort)0;
                ushort h3v = ok ? srcp[3 * HW] : (ushort)0;
                uint2 hv;
                hv.x = (uint)h0 | ((uint)h1 << 16);
                hv.y = (uint)h2 | ((uint)h3v << 16);
                uint byte = (uint)cell * 128 + (uint)c * 32 + (uint)w * 8;
                byte ^= ((uint)(cell & 7)) << 4;
                *(uint2*)(lds + byte) = hv;
            }
        }
    }
    __syncthreads();   // the ONLY barrier: A tile + sv-pad visible; A read-only after

    f32x16 zero16;
    #pragma unroll
    for (int r = 0; r < 16; ++r) zero16[r] = 0.f;

    f32x16 cd[2][2];
    #pragma unroll
    for (int a = 0; a < 2; ++a)
        #pragma unroll
        for (int b = 0; b < 2; ++b) cd[a][b] = zero16;

    int xb2 = col & 15;
    int rb0 = 4 * w + ((col >> 4) & 1);

    for (int sp = 0; sp < 8; ++sp) {
        int g0 = sp * 2;
        f32x16 c4[2][2];
        #pragma unroll
        for (int a = 0; a < 2; ++a)
            #pragma unroll
            for (int b = 0; b < 2; ++b) c4[a][b] = zero16;

        #pragma unroll 1
        for (int c = 0; c < 4; ++c) {
            #pragma unroll
            for (int t = 0; t < 9; ++t) {
                const int ky = t / 3, kx = t % 3;
                size_t bb = (size_t)((c * 9 + t) * 16) * 512 + (size_t)lane * 8;
                bf16x8 bh0 = *(const bf16x8*)(w4hi + bb + (size_t)g0 * 512);
                bf16x8 bh1 = *(const bf16x8*)(w4hi + bb + (size_t)(g0 + 1) * 512);
                #pragma unroll
                for (int f = 0; f < 2; ++f) {
                    int cell = (rb0 + 2 * f + ky) * 18 + xb2 + kx;
                    uint byte = (uint)cell * 128 + (uint)(2 * c + khalf) * 16;
                    byte ^= ((uint)(cell & 7)) << 4;
                    bf16x8 ah = *(const bf16x8*)(lds + byte);
                    c4[0][f] = mfma32(ah, bh0, c4[0][f]);
                    c4[1][f] = mfma32(ah, bh1, c4[1][f]);
                }
            }
        }

        #pragma unroll
        for (int gg = 0; gg < 2; ++gg) {
            int g = g0 + gg;
            __builtin_amdgcn_sched_barrier(0);   // fence: prev gemm sv reads vs new writes (wave-private LDS)
            if (col < 27) {
                float pb = pb4[g * 32 + col];
                #pragma unroll
                for (int f = 0; f < 2; ++f)
                    #pragma unroll
                    for (int r = 0; r < 16; ++r) {
                        int pxl = 64 * w + 32 * f + (r & 3) + 8 * (r >> 2) + 4 * khalf;
                        float v = c4[gg][f][r] + pb;
                        v = (col < 18) ? MRM_ * fast_tanh(v) : 1.f / (1.f + __expf(-v));
                        OMBH[pxl * 30 + col] = (_Float16)v;
                    }
            }
            __builtin_amdgcn_sched_barrier(0);   // fence: OMB writes vs sampler reads
            // ---- sampler: 1 px per thread; group-NHWC -> 4 corner uint2 loads/tap, line-coherent
            {
                int px = tid;
                float Yf = (float)Yp, Xf = (float)Xp;
                const ushort* xg = xtn + (size_t)g * HW * 4;
                #pragma unroll
                for (int k = 0; k < 9; ++k) {
                    float oy = (float)OMBH[px * 30 + 2 * k] + fyr;
                    float ox = (float)OMBH[px * 30 + 2 * k + 1] + fxr;
                    float mk = (float)OMBH[px * 30 + 18 + k];
                    Bil b = bil(Yf - 1.f + (float)(k / 3) + oy,
                                Xf - 1.f + (float)(k % 3) + ox);
                    uint2 q00 = *(const uint2*)(xg + (size_t)b.i00 * 4);
                    uint2 q01 = *(const uint2*)(xg + (size_t)b.i01 * 4);
                    uint2 q10 = *(const uint2*)(xg + (size_t)b.i10 * 4);
                    uint2 q11 = *(const uint2*)(xg + (size_t)b.i11 * 4);
                    float s0 = b.m00 * blo(q00.x) + b.m01 * blo(q01.x)
                             + b.m10 * blo(q10.x) + b.m11 * blo(q11.x);
                    float s1 = b.m00 * bhi(q00.x) + b.m01 * bhi(q01.x)
                             + b.m10 * bhi(q10.x) + b.m11 * bhi(q11.x);
                    float s2 = b.m00 * blo(q00.y) + b.m01 * blo(q01.y)
                             + b.m10 * blo(q10.y) + b.m11 * blo(q11.y);
                    float s3 = b.m00 * bhi(q00.y) + b.m01 * bhi(q01.y)
                             + b.m10 * bhi(q10.y) + b.m11 * bhi(q11.y);
                    uint2 pk;
                    pk.x = (uint)bfrn(s0 * mk) | ((uint)bfrn(s1 * mk) << 16);
                    pk.y = (uint)bfrn(s2 * mk) | ((uint)bfrn(s3 * mk) << 16);
                    *(uint2*)(lds + (SV_OFF + (uint)px * 96 + (uint)k * 8)) = pk;
                }
            }
            __builtin_amdgcn_sched_barrier(0);   // fence: sv uint2 stores vs bf16x8 loads
            #pragma unroll
            for (int kst = 0; kst < 3; ++kst) {
                size_t dbb = (size_t)((g * 3 + kst) * 2) * 512 + (size_t)lane * 8;
                bf16x8 b0 = *(const bf16x8*)(dwtb + dbb);
                bf16x8 b1 = *(const bf16x8*)(dwtb + dbb + 512);
                #pragma unroll
                for (int f = 0; f < 2; ++f) {
                    int pxl = 64 * w + 32 * f + col;
                    uint byte = SV_OFF + (uint)pxl * 96 + (uint)(kst * 2 + khalf) * 16;
                    bf16x8 a = *(const bf16x8*)(lds + byte);
                    cd[f][0] = mfma32(a, b0, cd[f][0]);
                    cd[f][1] = mfma32(a, b1, cd[f][1]);
                }
            }
        }
    }

    float* base = (n < 5) ? outb + (size_t)n * 64 * HW
                          : outb + (size_t)(n + 2) * 64 * HW;
    #pragma unroll
    for (int f = 0; f < 2; ++f)
        #pragma unroll
        for (int nf = 0; nf < 2; ++nf) {
            int oc = nf * 32 + col;
            float bias = db[oc];
            #pragma unroll
            for (int r = 0; r < 16; ++r) {
                int pxl = 64 * w + 32 * f + (r & 3) + 8 * (r >> 2) + 4 * khalf;
                int y = by * 16 + (pxl >> 4), xx = bx * 16 + (pxl & 15);
                base[(size_t)oc * HW + y * W_ + xx] = cd[f][nf][r] + bias;
            }
        }
}

extern "C" void kernel_launch(void* const* d_in, const int* in_sizes, int n_in,
                              void* d_out, int out_size, void* d_ws, size_t ws_size,
                              hipStream_t stream) {
    (void)in_sizes; (void)n_in; (void)out_size; (void)ws_size;
    const float* x   = (const float*)d_in[0];
    const float* fb  = (const float*)d_in[1];
    const float* ff  = (const float*)d_in[2];
    const float* cw1 = (const float*)d_in[3];
    const float* cb1 = (const float*)d_in[4];
    const float* cw2 = (const float*)d_in[5];
    const float* cb2 = (const float*)d_in[6];
    const float* cw3 = (const float*)d_in[7];
    const float* cb3 = (const float*)d_in[8];
    const float* cw4 = (const float*)d_in[9];
    const float* cb4 = (const float*)d_in[10];
    const float* dw  = (const float*)d_in[11];
    const float* db  = (const float*)d_in[12];
    float* out = (float*)d_out;

    // ws: h1(bf16 21MB, later reused as x_t) | h3(bf16 21MB) | w1t | w2t | w3t | w4t | dwtb | pb4
    ushort* h1b  = (ushort*)d_ws;
    ushort* h3b  = h1b + 10485760;
    ushort* w1t  = h3b + 10485760;
    ushort* w2t  = w1t + W1T_N;
    ushort* w3t  = w2t + W2T_N;
    ushort* w4t  = w3t + W2T_N;
    ushort* dwtb = w4t + W4_N;
    float*  pb4  = (float*)(dwtb + DWT_N);
    ushort* xtb  = h1b;   // x_t overlays h1 (h1 dead after conv2; k_xt launches after conv2)
    // d_out doubles as scratch: warped(bf16 21MB) | h2(bf16 21MB)
    ushort* wpb  = (ushort*)d_out;
    ushort* h2b  = wpb + 10485760;

    (void)hipFuncSetAttribute((const void*)k_dcn7,
                              hipFuncAttributeMaxDynamicSharedMemorySize, LDS_TOT);

    k_prep<<<1958, 256, 0, stream>>>(cw1, cw2, cw3, cw4, cb4, dw,
                                     w1t, w2t, w3t, w4t, dwtb, pb4);
    k_warp<<<(NP * HW) / 256, 256, 0, stream>>>(x, fb, ff, wpb);
    k_convm<9, 0><<<640, 256, 0, stream>>>(wpb, x, fb, ff, w1t, cb1, h1b);
    k_convm<4, 1><<<640, 256, 0, stream>>>(h1b, x, fb, ff, w2t, cb2, h2b);
    k_xt<<<(6 * HW) / 256, 256, 0, stream>>>(x, xtb);   // after conv2 (h1 dead), before k_dcn
    k_convm<4, 1><<<640, 256, 0, stream>>>(h2b, x, fb, ff, w3t, cb3, h3b);

    // zero output frame slots 5 (backward last) and 6 (forward first) — after conv3 consumed h2
    hipMemsetAsync((char*)d_out + (size_t)5 * C_ * HW * sizeof(float), 0, (size_t)C_ * HW * sizeof(float), stream);
    hipMemsetAsync((char*)d_out + (size_t)6 * C_ * HW * sizeof(float), 0, (size_t)C_ * HW * sizeof(float), stream);

    k_dcn7<<<640, 256, LDS_TOT, stream>>>(h3b, xtb, fb, ff, w4t, dwtb, pb4, db, out);
}

// Round 9
// 597.432 us; speedup vs baseline: 3.7591x; 1.0346x over previous
//
#include <hip/hip_runtime.h>
#include <math.h>

#define NP   10
#define C_   64
#define H_   128
#define W_   128
#define HW   (H_*W_)
#define MRM_ 10.0f

// k_dcn8 static LDS: A-halo 180 cells * 128 B, then OMB [128 px][30] f16
#define OMB8_OFF 23040u
#define LDS8_TOT 30720

// prep section sizes (ushort elems)
#define W1T_N 82944    // 9 chunks * 9 taps * 2 nf * 512
#define W2T_N 36864    // 4 * 9 * 2 * 512
#define W4_N  294912
#define DWT_N 49152

typedef __bf16 bf16x8 __attribute__((ext_vector_type(8)));
typedef float  f32x16 __attribute__((ext_vector_type(16)));

__device__ __forceinline__ f32x16 mfma32(bf16x8 a, bf16x8 b, f32x16 c) {
    return __builtin_amdgcn_mfma_f32_32x32x16_bf16(a, b, c, 0, 0, 0);
}

__device__ __forceinline__ ushort bfrn(float f) {
    uint u = __builtin_bit_cast(uint, f);
    u += 0x7FFFu + ((u >> 16) & 1u);
    return (ushort)(u >> 16);
}
__device__ __forceinline__ float blo(uint u) { return __builtin_bit_cast(float, u << 16); }
__device__ __forceinline__ float bhi(uint u) { return __builtin_bit_cast(float, u & 0xFFFF0000u); }
__device__ __forceinline__ float fast_tanh(float x) {
    float e = __expf(2.f * x);
    return 1.f - 2.f / (e + 1.f);
}

// ---------- frame-mapping helpers ----------
__device__ __forceinline__ const float* xi_base(const float* x, int n) {
    int f = (n < 5) ? (n + 1) : (n - 5);
    return x + (size_t)f * C_ * HW;
}
__device__ __forceinline__ const float* cur_base(const float* x, int n) {
    int f = (n < 5) ? n : (n - 4);
    return x + (size_t)f * C_ * HW;
}
__device__ __forceinline__ const float* fl_base(const float* fb, const float* ff, int n) {
    return (n < 5) ? (fb + (size_t)n * 2 * HW) : (ff + (size_t)(n - 5) * 2 * HW);
}

// ---------- bilinear corner helper (zero padding outside) ----------
struct Bil { int i00, i01, i10, i11; float m00, m01, m10, m11; };
__device__ __forceinline__ Bil bil(float py, float px) {
    float y0f = floorf(py), x0f = floorf(px);
    int iy0 = (int)y0f, ix0 = (int)x0f;
    float ay = py - y0f, ax = px - x0f;
    bool v0y = (unsigned)iy0 < (unsigned)H_;
    bool v1y = (unsigned)(iy0 + 1) < (unsigned)H_;
    bool v0x = (unsigned)ix0 < (unsigned)W_;
    bool v1x = (unsigned)(ix0 + 1) < (unsigned)W_;
    int cy0 = min(max(iy0, 0), H_ - 1), cy1 = min(max(iy0 + 1, 0), H_ - 1);
    int cx0 = min(max(ix0, 0), W_ - 1), cx1 = min(max(ix0 + 1, 0), W_ - 1);
    Bil r;
    r.m00 = (1.f - ay) * (1.f - ax) * (float)(v0y && v0x);
    r.m01 = (1.f - ay) * ax         * (float)(v0y && v1x);
    r.m10 = ay * (1.f - ax)         * (float)(v1y && v0x);
    r.m11 = ay * ax                 * (float)(v1y && v1x);
    r.i00 = cy0 * W_ + cx0; r.i01 = cy0 * W_ + cx1;
    r.i10 = cy1 * W_ + cx0; r.i11 = cy1 * W_ + cx1;
    return r;
}

// ---------- MFMA fragment-order weight prep (conv1-4 + dcn + bias) ----------
__global__ __launch_bounds__(256) void k_prep(
        const float* __restrict__ cw1, const float* __restrict__ cw2,
        const float* __restrict__ cw3, const float* __restrict__ cw4,
        const float* __restrict__ cb4, const float* __restrict__ dw,
        ushort* __restrict__ w1t, ushort* __restrict__ w2t,
        ushort* __restrict__ w3t, ushort* __restrict__ w4t,
        ushort* __restrict__ dwtb, float* __restrict__ pb4) {
    int id = blockIdx.x * 256 + threadIdx.x;
    if (id < W1T_N) {
        int blk = id >> 9, e = id & 511;
        int c = blk / 18, r = blk % 18; int t = r >> 1, nf = r & 1;
        int l = e >> 3, j = e & 7;
        int ci = c * 16 + (l >> 5) * 8 + j;
        int oc = nf * 32 + (l & 31);
        w1t[id] = (ci < 130) ? bfrn(cw1[((size_t)oc * 130 + ci) * 9 + t]) : (ushort)0;
        return;
    }
    id -= W1T_N;
    if (id < W2T_N) {
        int blk = id >> 9, e = id & 511;
        int c = blk / 18, r = blk % 18; int t = r >> 1, nf = r & 1;
        int l = e >> 3, j = e & 7;
        int ci = c * 16 + (l >> 5) * 8 + j;
        int oc = nf * 32 + (l & 31);
        w2t[id] = bfrn(cw2[((size_t)oc * 64 + ci) * 9 + t]);
        return;
    }
    id -= W2T_N;
    if (id < W2T_N) {
        int blk = id >> 9, e = id & 511;
        int c = blk / 18, r = blk % 18; int t = r >> 1, nf = r & 1;
        int l = e >> 3, j = e & 7;
        int ci = c * 16 + (l >> 5) * 8 + j;
        int oc = nf * 32 + (l & 31);
        w3t[id] = bfrn(cw3[((size_t)oc * 64 + ci) * 9 + t]);
        return;
    }
    id -= W2T_N;
    if (id < W4_N) {
        int blk = id >> 9, e = id & 511;
        int c = blk / 144, r = blk - c * 144;
        int t = r >> 4, g = r & 15;
        int l = e >> 3, j = e & 7;
        int nn = l & 31, kh = l >> 5;
        int ci = c * 16 + kh * 8 + j;
        int ch = (nn < 18) ? g * 18 + nn : (nn < 27 ? 288 + g * 9 + (nn - 18) : -1);
        float v = (ch >= 0) ? cw4[((size_t)ch * 64 + ci) * 9 + t] : 0.f;
        w4t[id] = bfrn(v);
        return;
    }
    id -= W4_N;
    if (id < DWT_N) {
        int blk = id >> 9, e = id & 511;
        int g = blk / 6, r = blk - g * 6;
        int kst = r >> 1, nf = r & 1;
        int l = e >> 3, j = e & 7;
        int kk = kst * 16 + (l >> 5) * 8 + j;
        int oc = nf * 32 + (l & 31);
        float v = (kk < 36) ? dw[((size_t)oc * 64 + g * 4 + (kk & 3)) * 9 + (kk >> 2)] : 0.f;
        dwtb[id] = bfrn(v);
        return;
    }
    id -= DWT_N;
    if (id < 512) {
        int g = id >> 5, nn = id & 31;
        int ch = (nn < 18) ? g * 18 + nn : (nn < 27 ? 288 + g * 9 + (nn - 18) : -1);
        pb4[id] = (ch >= 0) ? cb4[ch] : 0.f;
    }
}

// ---------- flow warp (writes bf16 planes) ----------
__global__ __launch_bounds__(256) void k_warp(
        const float* __restrict__ x, const float* __restrict__ fb,
        const float* __restrict__ ff, ushort* __restrict__ warped) {
    int gid = blockIdx.x * 256 + threadIdx.x;
    int n = gid / HW, pos = gid % HW;
    int y = pos / W_, xx = pos % W_;
    const float* fl = fl_base(fb, ff, n);
    float fx = fl[pos], fy = fl[HW + pos];
    Bil b = bil((float)y + fy, (float)xx + fx);
    const float* xb = xi_base(x, n);
    ushort* wout = warped + (size_t)n * C_ * HW + pos;
    for (int c = 0; c < C_; ++c) {
        const float* p = xb + c * HW;
        wout[c * HW] = bfrn(b.m00 * p[b.i00] + b.m01 * p[b.i01]
                          + b.m10 * p[b.i10] + b.m11 * p[b.i11]);
    }
}

// ---------- NCHW f32 -> per-GROUP NHWC bf16: xt[f][g][HW][4ch] ----------
__global__ __launch_bounds__(256) void k_xt(
        const float* __restrict__ x, ushort* __restrict__ xt) {
    int gid = blockIdx.x * 256 + threadIdx.x;   // 6*HW threads
    int f = gid / HW, pos = gid % HW;
    const float* src = x + (size_t)f * C_ * HW + pos;
    ushort* dst = xt + (size_t)f * 16 * HW * 4;
    #pragma unroll
    for (int g = 0; g < 16; ++g) {
        uint2 v;
        ushort h0 = bfrn(src[(g * 4 + 0) * HW]);
        ushort h1 = bfrn(src[(g * 4 + 1) * HW]);
        ushort h2 = bfrn(src[(g * 4 + 2) * HW]);
        ushort h3 = bfrn(src[(g * 4 + 3) * HW]);
        v.x = (uint)h0 | ((uint)h1 << 16);
        v.y = (uint)h2 | ((uint)h3 << 16);
        *(uint2*)(dst + ((size_t)g * HW + pos) * 4) = v;
    }
}

// ================== MFMA 3x3 conv, 64 out channels, LeakyReLU, bf16 planes ==================
template<int NCHUNK, int SRC>
__global__ __launch_bounds__(256, 3) void k_convm(
        const ushort* __restrict__ inb, const float* __restrict__ x,
        const float* __restrict__ fb, const float* __restrict__ ff,
        const ushort* __restrict__ wt, const float* __restrict__ bias,
        ushort* __restrict__ outp) {
    __shared__ __align__(16) char ldsb[41472];
    int tid = threadIdx.x;
    int lane = tid & 63, w = tid >> 6;
    int id = (blockIdx.x & 7) * 80 + (blockIdx.x >> 3);   // bijective XCD swizzle (640%8==0)
    int bx = id & 7, by = (id >> 3) & 7, n = id >> 6;
    int col = lane & 31, khalf = lane >> 5;

    const float* flp = fl_base(fb, ff, n);
    const float* curp = cur_base(x, n);

    f32x16 acc[2][2];
    #pragma unroll
    for (int a = 0; a < 2; ++a)
        #pragma unroll
        for (int b = 0; b < 2; ++b)
            #pragma unroll
            for (int r = 0; r < 16; ++r) acc[a][b][r] = 0.f;

    int xb2 = col & 15;
    int rb0 = 4 * w + ((col >> 4) & 1);
    const int NPASS = (NCHUNK + 3) / 4;

    #pragma unroll
    for (int p = 0; p < NPASS; ++p) {
        const int c0 = 4 * p;
        const int cN = (NCHUNK - c0 >= 4) ? 4 : (NCHUNK - c0);
        __syncthreads();   // previous pass sweep reads done (also fences TBAA reorder)
        for (int cc = 0; cc < cN; ++cc) {
            int chunk = c0 + cc;
            int cbase = chunk * 16 + w * 4;
            for (int v = 0; v < 6; ++v) {
                int cell = v * 64 + lane;
                if (cell < 324) {
                    int cy = cell / 18, cx = cell - cy * 18;
                    int gy = by * 16 + cy - 1, gx = bx * 16 + cx - 1;
                    bool ok = ((unsigned)gy < 128u) && ((unsigned)gx < 128u);
                    int pos = gy * W_ + gx;
                    uint2 hv; hv.x = hv.y = 0;
                    if (SRC == 1 || chunk < 4) {
                        const ushort* sp = inb + ((size_t)n * 64 + cbase) * HW + pos;
                        ushort h0 = ok ? sp[0] : (ushort)0;
                        ushort h1 = ok ? sp[HW] : (ushort)0;
                        ushort h2 = ok ? sp[2 * HW] : (ushort)0;
                        ushort h3 = ok ? sp[3 * HW] : (ushort)0;
                        hv.x = (uint)h0 | ((uint)h1 << 16);
                        hv.y = (uint)h2 | ((uint)h3 << 16);
                    } else if (chunk < 8) {
                        const float* sp = curp + (size_t)(cbase - 64) * HW + pos;
                        ushort h0 = bfrn(ok ? sp[0] : 0.f);
                        ushort h1 = bfrn(ok ? sp[HW] : 0.f);
                        ushort h2 = bfrn(ok ? sp[2 * HW] : 0.f);
                        ushort h3 = bfrn(ok ? sp[3 * HW] : 0.f);
                        hv.x = (uint)h0 | ((uint)h1 << 16);
                        hv.y = (uint)h2 | ((uint)h3 << 16);
                    } else {
                        float v0 = 0.f, v1 = 0.f;
                        if (w == 0 && ok) { v0 = flp[pos]; v1 = flp[HW + pos]; }
                        hv.x = (uint)bfrn(v0) | ((uint)bfrn(v1) << 16);
                    }
                    uint byte = (uint)cell * 128 + (uint)cc * 32 + (uint)w * 8;
                    byte ^= ((uint)(cell & 7)) << 4;
                    *(uint2*)(ldsb + byte) = hv;
                }
            }
        }
        __syncthreads();
        for (int cc = 0; cc < cN; ++cc) {
            #pragma unroll
            for (int t = 0; t < 9; ++t) {
                const int ky = t / 3, kx = t % 3;
                size_t bb = (size_t)(((c0 + cc) * 9 + t) * 2) * 512 + (size_t)lane * 8;
                bf16x8 b0 = *(const bf16x8*)(wt + bb);
                bf16x8 b1 = *(const bf16x8*)(wt + bb + 512);
                #pragma unroll
                for (int f = 0; f < 2; ++f) {
                    int cell = (rb0 + 2 * f + ky) * 18 + xb2 + kx;
                    uint byte = (uint)cell * 128 + (uint)(2 * cc + khalf) * 16;
                    byte ^= ((uint)(cell & 7)) << 4;
                    bf16x8 a = *(const bf16x8*)(ldsb + byte);
                    acc[f][0] = mfma32(a, b0, acc[f][0]);
                    acc[f][1] = mfma32(a, b1, acc[f][1]);
                }
            }
        }
    }

    ushort* op = outp + (size_t)n * 64 * HW;
    #pragma unroll
    for (int f = 0; f < 2; ++f)
        #pragma unroll
        for (int nf = 0; nf < 2; ++nf) {
            int oc = nf * 32 + col;
            float bs = bias[oc];
            #pragma unroll
            for (int r = 0; r < 16; ++r) {
                int pxl = 64 * w + 32 * f + (r & 3) + 8 * (r >> 2) + 4 * khalf;
                int y = by * 16 + (pxl >> 4), xx = bx * 16 + (pxl & 15);
                float v = acc[f][nf][r] + bs;
                v = (v >= 0.f) ? v : 0.1f * v;
                op[(size_t)oc * HW + y * W_ + xx] = bfrn(v);
            }
        }
}

// ================== fused conv4 + sampler + DCN GEMM, 16x8 tile / 2 waves / 5 blocks/CU ==================
// sv now lives in REGISTERS: producer thread=px holds pk[9] (uint2/tap); the DCN GEMM A-frag
// is an intra-wave transpose done with ds_bpermute (src lane = 32f + (lane&31)) followed by a
// cndmask on the DEST lane's khalf (selection must be post-permute: source lanes have the
// wrong khalf). Frag order matches the old LDS sv layout exactly.
// LDS: A-halo [180 cells][64ci] bf16 XOR-swizzled (23040 B) + OMB [128 px][30] f16 (7680 B).
// 30720 B -> 5 blocks/CU; grid 1280 = 256 CU * 5: all blocks resident, zero dispatch tail.
__global__ __launch_bounds__(128, 2) void k_dcn8(
        const ushort* __restrict__ h3, const ushort* __restrict__ xt,
        const float* __restrict__ fb, const float* __restrict__ ff,
        const ushort* __restrict__ w4hi,
        const ushort* __restrict__ dwtb, const float* __restrict__ pb4,
        const float* __restrict__ db, float* __restrict__ outb) {
    __shared__ __align__(16) char lds[LDS8_TOT];
    _Float16* OMBH = (_Float16*)(lds + OMB8_OFF);   // [px 128][30] f16

    int tid = threadIdx.x;
    int lane = tid & 63, w = tid >> 6;          // w in {0,1}
    // bijective XCD swizzle: 1280 blocks, 8 XCDs -> 160 consecutive ids each
    int id = (blockIdx.x & 7) * 160 + (blockIdx.x >> 3);
    int bx = id & 15, by = (id >> 4) & 7, n = id >> 7;   // 16 x-tiles * 8 y-tiles * 10
    int col = lane & 31, khalf = lane >> 5;

    const ushort* h3n = h3 + (size_t)n * 64 * HW;
    const float* fl = fl_base(fb, ff, n);
    int fxi = (n < 5) ? (n + 1) : (n - 5);
    const ushort* xtn = xt + (size_t)fxi * 16 * HW * 4;

    int Yp = by * 16 + (tid >> 3), Xp = bx * 8 + (tid & 7);
    float fxr = fl[Yp * W_ + Xp];
    float fyr = fl[HW + Yp * W_ + Xp];

    // ---- stage full h3 halo tile: [cell 180][ci 64] bf16, XOR-swizzled 16B units
    // wave w handles ci w*8..w*8+7 of each 16-ci chunk (bytes c*32 + w*16 .. +15)
    for (int c = 0; c < 4; ++c) {
        for (int v = 0; v < 3; ++v) {
            int cell = v * 64 + lane;
            if (cell < 180) {
                int cy = cell / 10, cx = cell - cy * 10;
                int gy = by * 16 + cy - 1, gx = bx * 8 + cx - 1;
                bool ok = ((unsigned)gy < 128u) && ((unsigned)gx < 128u);
                const ushort* srcp = h3n + (size_t)(c * 16 + w * 8) * HW + gy * W_ + gx;
                uint2 hv0, hv1;
                ushort q0 = ok ? srcp[0] : (ushort)0;
                ushort q1 = ok ? srcp[HW] : (ushort)0;
                ushort q2 = ok ? srcp[2 * HW] : (ushort)0;
                ushort q3 = ok ? srcp[3 * HW] : (ushort)0;
                ushort q4 = ok ? srcp[4 * HW] : (ushort)0;
                ushort q5 = ok ? srcp[5 * HW] : (ushort)0;
                ushort q6 = ok ? srcp[6 * HW] : (ushort)0;
                ushort q7 = ok ? srcp[7 * HW] : (ushort)0;
                hv0.x = (uint)q0 | ((uint)q1 << 16);
                hv0.y = (uint)q2 | ((uint)q3 << 16);
                hv1.x = (uint)q4 | ((uint)q5 << 16);
                hv1.y = (uint)q6 | ((uint)q7 << 16);
                uint byte = (uint)cell * 128 + (uint)c * 32 + (uint)w * 16;
                byte ^= ((uint)(cell & 7)) << 4;
                *(uint2*)(lds + byte) = hv0;
                *(uint2*)(lds + byte + 8) = hv1;
            }
        }
    }
    __syncthreads();   // the ONLY barrier: A tile visible; read-only after

    f32x16 zero16;
    #pragma unroll
    for (int r = 0; r < 16; ++r) zero16[r] = 0.f;

    f32x16 cd[2][2];
    #pragma unroll
    for (int a = 0; a < 2; ++a)
        #pragma unroll
        for (int b = 0; b < 2; ++b) cd[a][b] = zero16;

    int colq = col >> 3;      // row within M-frag quarter
    int colx = col & 7;       // x within tile
    int ad0 = (lane & 31) * 4;

    for (int sp = 0; sp < 8; ++sp) {
        int g0 = sp * 2;
        f32x16 c4[2][2];
        #pragma unroll
        for (int a = 0; a < 2; ++a)
            #pragma unroll
            for (int b = 0; b < 2; ++b) c4[a][b] = zero16;

        // ---- conv4 MFMA sweep: A resident in LDS, B frags streamed from global (L2)
        #pragma unroll 1
        for (int c = 0; c < 4; ++c) {
            #pragma unroll
            for (int t = 0; t < 9; ++t) {
                const int ky = t / 3, kx = t % 3;
                size_t bb = (size_t)((c * 9 + t) * 16) * 512 + (size_t)lane * 8;
                bf16x8 bh0 = *(const bf16x8*)(w4hi + bb + (size_t)g0 * 512);
                bf16x8 bh1 = *(const bf16x8*)(w4hi + bb + (size_t)(g0 + 1) * 512);
                #pragma unroll
                for (int f = 0; f < 2; ++f) {
                    int cell = (8 * w + 4 * f + colq + ky) * 10 + colx + kx;
                    uint byte = (uint)cell * 128 + (uint)(2 * c + khalf) * 16;
                    byte ^= ((uint)(cell & 7)) << 4;
                    bf16x8 ah = *(const bf16x8*)(lds + byte);
                    c4[0][f] = mfma32(ah, bh0, c4[0][f]);
                    c4[1][f] = mfma32(ah, bh1, c4[1][f]);
                }
            }
        }

        #pragma unroll
        for (int gg = 0; gg < 2; ++gg) {
            int g = g0 + gg;
            __builtin_amdgcn_sched_barrier(0);   // fence: prev sampler OMB reads vs new writes
            if (col < 27) {
                float pb = pb4[g * 32 + col];
                #pragma unroll
                for (int f = 0; f < 2; ++f)
                    #pragma unroll
                    for (int r = 0; r < 16; ++r) {
                        int pxl = 64 * w + 32 * f + (r & 3) + 8 * (r >> 2) + 4 * khalf;
                        float v = c4[gg][f][r] + pb;
                        v = (col < 18) ? MRM_ * fast_tanh(v) : 1.f / (1.f + __expf(-v));
                        OMBH[pxl * 30 + col] = (_Float16)v;
                    }
            }
            __builtin_amdgcn_sched_barrier(0);   // fence: OMB writes vs sampler reads
            // ---- sampler: 1 px per thread; results kept in registers (pkx/pky per tap)
            int pkx[9], pky[9];
            {
                int px = tid;
                float Yf = (float)Yp, Xf = (float)Xp;
                const ushort* xg = xtn + (size_t)g * HW * 4;
                #pragma unroll
                for (int k = 0; k < 9; ++k) {
                    float oy = (float)OMBH[px * 30 + 2 * k] + fyr;
                    float ox = (float)OMBH[px * 30 + 2 * k + 1] + fxr;
                    float mk = (float)OMBH[px * 30 + 18 + k];
                    Bil b = bil(Yf - 1.f + (float)(k / 3) + oy,
                                Xf - 1.f + (float)(k % 3) + ox);
                    uint2 q00 = *(const uint2*)(xg + (size_t)b.i00 * 4);
                    uint2 q01 = *(const uint2*)(xg + (size_t)b.i01 * 4);
                    uint2 q10 = *(const uint2*)(xg + (size_t)b.i10 * 4);
                    uint2 q11 = *(const uint2*)(xg + (size_t)b.i11 * 4);
                    float s0 = b.m00 * blo(q00.x) + b.m01 * blo(q01.x)
                             + b.m10 * blo(q10.x) + b.m11 * blo(q11.x);
                    float s1 = b.m00 * bhi(q00.x) + b.m01 * bhi(q01.x)
                             + b.m10 * bhi(q10.x) + b.m11 * bhi(q11.x);
                    float s2 = b.m00 * blo(q00.y) + b.m01 * blo(q01.y)
                             + b.m10 * blo(q10.y) + b.m11 * blo(q11.y);
                    float s3 = b.m00 * bhi(q00.y) + b.m01 * bhi(q01.y)
                             + b.m10 * bhi(q10.y) + b.m11 * bhi(q11.y);
                    pkx[k] = (int)((uint)bfrn(s0 * mk) | ((uint)bfrn(s1 * mk) << 16));
                    pky[k] = (int)((uint)bfrn(s2 * mk) | ((uint)bfrn(s3 * mk) << 16));
                }
            }
            // ---- DCN GEMM: A frags via intra-wave bpermute transpose, B from global
            #pragma unroll
            for (int kst = 0; kst < 3; ++kst) {
                size_t dbb = (size_t)((g * 3 + kst) * 2) * 512 + (size_t)lane * 8;
                bf16x8 b0 = *(const bf16x8*)(dwtb + dbb);
                bf16x8 b1 = *(const bf16x8*)(dwtb + dbb + 512);
                #pragma unroll
                for (int f = 0; f < 2; ++f) {
                    int ad = ad0 + f * 128;
                    uint a0, a1, a2, a3;
                    if (kst < 2) {
                        const int t0 = kst * 4;
                        uint x0 = (uint)__builtin_amdgcn_ds_bpermute(ad, pkx[t0]);
                        uint y0 = (uint)__builtin_amdgcn_ds_bpermute(ad, pky[t0]);
                        uint x1 = (uint)__builtin_amdgcn_ds_bpermute(ad, pkx[t0 + 1]);
                        uint y1 = (uint)__builtin_amdgcn_ds_bpermute(ad, pky[t0 + 1]);
                        uint x2 = (uint)__builtin_amdgcn_ds_bpermute(ad, pkx[t0 + 2]);
                        uint y2 = (uint)__builtin_amdgcn_ds_bpermute(ad, pky[t0 + 2]);
                        uint x3 = (uint)__builtin_amdgcn_ds_bpermute(ad, pkx[t0 + 3]);
                        uint y3 = (uint)__builtin_amdgcn_ds_bpermute(ad, pky[t0 + 3]);
                        a0 = khalf ? x2 : x0;
                        a1 = khalf ? y2 : y0;
                        a2 = khalf ? x3 : x1;
                        a3 = khalf ? y3 : y1;
                    } else {
                        uint x8 = (uint)__builtin_amdgcn_ds_bpermute(ad, pkx[8]);
                        uint y8 = (uint)__builtin_amdgcn_ds_bpermute(ad, pky[8]);
                        a0 = khalf ? 0u : x8;
                        a1 = khalf ? 0u : y8;
                        a2 = 0u; a3 = 0u;
                    }
                    uint4 av; av.x = a0; av.y = a1; av.z = a2; av.w = a3;
                    bf16x8 a = __builtin_bit_cast(bf16x8, av);
                    cd[f][0] = mfma32(a, b0, cd[f][0]);
                    cd[f][1] = mfma32(a, b1, cd[f][1]);
                }
            }
        }
    }

    float* base = (n < 5) ? outb + (size_t)n * 64 * HW
                          : outb + (size_t)(n + 2) * 64 * HW;
    #pragma unroll
    for (int f = 0; f < 2; ++f)
        #pragma unroll
        for (int nf = 0; nf < 2; ++nf) {
            int oc = nf * 32 + col;
            float bias = db[oc];
            #pragma unroll
            for (int r = 0; r < 16; ++r) {
                int pxl = 64 * w + 32 * f + (r & 3) + 8 * (r >> 2) + 4 * khalf;
                int y = by * 16 + (pxl >> 3), xx = bx * 8 + (pxl & 7);
                base[(size_t)oc * HW + y * W_ + xx] = cd[f][nf][r] + bias;
            }
        }
}

extern "C" void kernel_launch(void* const* d_in, const int* in_sizes, int n_in,
                              void* d_out, int out_size, void* d_ws, size_t ws_size,
                              hipStream_t stream) {
    (void)in_sizes; (void)n_in; (void)out_size; (void)ws_size;
    const float* x   = (const float*)d_in[0];
    const float* fb  = (const float*)d_in[1];
    const float* ff  = (const float*)d_in[2];
    const float* cw1 = (const float*)d_in[3];
    const float* cb1 = (const float*)d_in[4];
    const float* cw2 = (const float*)d_in[5];
    const float* cb2 = (const float*)d_in[6];
    const float* cw3 = (const float*)d_in[7];
    const float* cb3 = (const float*)d_in[8];
    const float* cw4 = (const float*)d_in[9];
    const float* cb4 = (const float*)d_in[10];
    const float* dw  = (const float*)d_in[11];
    const float* db  = (const float*)d_in[12];
    float* out = (float*)d_out;

    // ws: h1(bf16 21MB, later reused as x_t) | h3(bf16 21MB) | w1t | w2t | w3t | w4t | dwtb | pb4
    ushort* h1b  = (ushort*)d_ws;
    ushort* h3b  = h1b + 10485760;
    ushort* w1t  = h3b + 10485760;
    ushort* w2t  = w1t + W1T_N;
    ushort* w3t  = w2t + W2T_N;
    ushort* w4t  = w3t + W2T_N;
    ushort* dwtb = w4t + W4_N;
    float*  pb4  = (float*)(dwtb + DWT_N);
    ushort* xtb  = h1b;   // x_t overlays h1 (h1 dead after conv2; k_xt launches after conv2)
    // d_out doubles as scratch: warped(bf16 21MB) | h2(bf16 21MB)
    ushort* wpb  = (ushort*)d_out;
    ushort* h2b  = wpb + 10485760;

    k_prep<<<1958, 256, 0, stream>>>(cw1, cw2, cw3, cw4, cb4, dw,
                                     w1t, w2t, w3t, w4t, dwtb, pb4);
    k_warp<<<(NP * HW) / 256, 256, 0, stream>>>(x, fb, ff, wpb);
    k_convm<9, 0><<<640, 256, 0, stream>>>(wpb, x, fb, ff, w1t, cb1, h1b);
    k_convm<4, 1><<<640, 256, 0, stream>>>(h1b, x, fb, ff, w2t, cb2, h2b);
    k_xt<<<(6 * HW) / 256, 256, 0, stream>>>(x, xtb);   // after conv2 (h1 dead), before k_dcn
    k_convm<4, 1><<<640, 256, 0, stream>>>(h2b, x, fb, ff, w3t, cb3, h3b);

    // zero output frame slots 5 (backward last) and 6 (forward first) — after conv3 consumed h2
    hipMemsetAsync((char*)d_out + (size_t)5 * C_ * HW * sizeof(float), 0, (size_t)C_ * HW * sizeof(float), stream);
    hipMemsetAsync((char*)d_out + (size_t)6 * C_ * HW * sizeof(float), 0, (size_t)C_ * HW * sizeof(float), stream);

    k_dcn8<<<1280, 128, 0, stream>>>(h3b, xtb, fb, ff, w4t, dwtb, pb4, db, out);
}